// Round 6
// baseline (496.341 us; speedup 1.0000x reference)
//
#include <hip/hip_runtime.h>
#include <hip/hip_bf16.h>
#include <math.h>

#define BATCH 2048
#define INDIM 512
#define HID   256
#define NRIM  16
#define VAL   400
#define ONUM  8
#define CH    4
#define CK    32
#define CV    256
#define KACT  8
#define K2P   704   // GRU K padded to multiple of 64 (672 -> 704)

typedef __hip_bfloat16 hbf;
typedef __attribute__((ext_vector_type(8))) __bf16 bf16x8;
typedef __attribute__((ext_vector_type(4))) float f32x4;

__device__ __forceinline__ float sigmoidf_(float x) { return 1.0f / (1.0f + expf(-x)); }

__device__ __forceinline__ unsigned packbf(float a, float b) {
    hbf ha = __float2bfloat16(a), hb = __float2bfloat16(b);
    unsigned short ua, ub;
    __builtin_memcpy(&ua, &ha, 2);
    __builtin_memcpy(&ub, &hb, 2);
    return ((unsigned)ub << 16) | ua;
}

#define GLL(g, l) __builtin_amdgcn_global_load_lds(                                   \
    (const __attribute__((address_space(1))) void*)(g),                               \
    (__attribute__((address_space(3))) void*)(l), 16, 0, 0)

// ---------------- K1s: scores, top-k mask, softmax p0 (16 batches / block) ---------
__global__ __launch_bounds__(256)
void k1s(const float* __restrict__ option, const float* __restrict__ p_w,
         const float* __restrict__ p_b, float* __restrict__ p0g, float* __restrict__ maskg)
{
    const int t  = threadIdx.x;
    const int bb = t >> 4, n = t & 15;
    const int b  = blockIdx.x * 16 + bb;
    __shared__ float sc[16][17];

    float s0 = p_b[n], s1 = 0.0f;
    #pragma unroll
    for (int o = 0; o < ONUM; ++o) {
        s0 = fmaf(option[(b * 2 + 0) * ONUM + o], p_w[o * NRIM + n], s0);
        s1 = fmaf(option[(b * 2 + 1) * ONUM + o], p_w[o * NRIM + n], s1);
    }
    sc[bb][n] = s0;
    __syncthreads();

    int rank = 0;
    #pragma unroll
    for (int m = 0; m < NRIM; ++m) {
        float sm = sc[bb][m];
        if (sm > s0 || (sm == s0 && m < n)) rank++;
    }
    float mk = (rank < KACT) ? 1.0f : 0.0f;
    float mx = fmaxf(s0, s1);
    float e0 = expf(s0 - mx), e1 = expf(s1 - mx);
    p0g[b * NRIM + n]   = e0 / (e0 + e1);
    maskg[b * NRIM + n] = mk;
}

// ---------------- x -> bf16 --------------------------------------------------------
__global__ __launch_bounds__(256)
void k_xb(const float* __restrict__ x, hbf* __restrict__ xB)
{
    const int i = blockIdx.x * 256 + threadIdx.x;
    float4 v = ((const float4*)x)[i];
    unsigned lo = packbf(v.x, v.y), hi = packbf(v.z, v.w);
    *(uint2*)(xB + (size_t)i * 4) = make_uint2(lo, hi);
}

// ---------------- K1b: A2[b][n][K2P] = [ bf16(hs) | masked inputs | 0 pad ] --------
__global__ __launch_bounds__(256)
void k1b_a2(const float* __restrict__ hs, const float* __restrict__ vl0,
            const float* __restrict__ p0g, const float* __restrict__ maskg,
            const float* __restrict__ value_b, hbf* __restrict__ A2)
{
    const int b = blockIdx.x;
    const int t = threadIdx.x;
    __shared__ float vS[VAL], bS[VAL];
    if (t < 100) {
        ((float4*)vS)[t] = ((const float4*)(vl0 + (size_t)b * 512))[t];
        ((float4*)bS)[t] = ((const float4*)value_b)[t];
    }
    __syncthreads();

    for (int n = 0; n < NRIM; ++n) {
        size_t ro = ((size_t)b * NRIM + n) * K2P;
        float p0 = p0g[b * NRIM + n], mk = maskg[b * NRIM + n];
        if (t < 128) {
            float2 hv = ((const float2*)(hs + ((size_t)b * NRIM + n) * HID))[t];
            ((unsigned*)(A2 + ro))[t] = packbf(hv.x, hv.y);
        } else if (t < 152) {
            ((unsigned*)(A2 + ro + 656))[t - 128] = 0;
        }
        if (t < 200) {
            float a0 = mk * (p0 * vS[2 * t]     + (1.0f - p0) * bS[2 * t]);
            float a1 = mk * (p0 * vS[2 * t + 1] + (1.0f - p0) * bS[2 * t + 1]);
            ((unsigned*)(A2 + ro + 256))[t] = packbf(a0, a1);
        }
    }
}

// ---------------- zero fill (bf16, nelem8 = count of 16B chunks) -------------------
__global__ __launch_bounds__(256)
void k_zero(hbf* __restrict__ p, long nelem8)
{
    long i = (long)blockIdx.x * 256 + threadIdx.x;
    if (i < nelem8) {
        uint4 z; z.x = 0; z.y = 0; z.z = 0; z.w = 0;
        ((uint4*)p)[i] = z;
    }
}

// ---------------- transpose+convert: dst[n][coff+cmap(c)][koff+k] = src[n][k][c] ---
__global__ __launch_bounds__(256)
void t_conv(const float* __restrict__ src, hbf* __restrict__ dst,
            int K, int C, long s_nstride, long d_nstride, int dstride,
            int koff, int coff, int cmode)
{
    const int n  = blockIdx.z;
    const int c0 = blockIdx.x * 32, k0 = blockIdx.y * 32;
    const int tx = threadIdx.x & 31, ty = threadIdx.x >> 5;
    __shared__ float tile[32][33];
    const float* s = src + (size_t)n * s_nstride;
    #pragma unroll
    for (int i = 0; i < 4; ++i) {
        int k = k0 + ty + i * 8, c = c0 + tx;
        tile[ty + i * 8][tx] = (k < K && c < C) ? s[(size_t)k * C + c] : 0.0f;
    }
    __syncthreads();
    hbf* d = dst + (size_t)n * d_nstride;
    #pragma unroll
    for (int i = 0; i < 4; ++i) {
        int c = c0 + ty + i * 8, k = k0 + tx;
        if (c < C && k < K) {
            int cc = coff + (cmode ? (c < 512 ? c : c + 256) : c);
            d[(size_t)cc * dstride + koff + k] = __float2bfloat16(tile[tx][ty + i * 8]);
        }
    }
}

// ------ MFMA GEMM core: BK=64, swizzled LDS (pre-swizzled global src, rule #21) ----
__device__ __forceinline__ void gemm_core64(const hbf* __restrict__ A, long lda,
                                            const hbf* __restrict__ B, long ldb,
                                            int K, short* As, short* Bs, f32x4 acc[4][4])
{
    const int t = threadIdx.x;
    const int w = t >> 6, lane = t & 63;
    const int l15 = lane & 15, l4 = lane >> 4;
    const int rl = lane >> 3;
    const int gu = (lane & 7) ^ rl;
    const int l7 = l15 & 7;

    for (int kk = 0; kk < K; kk += 64) {
        __syncthreads();
        #pragma unroll
        for (int q = 0; q < 4; ++q) {
            int row = q * 32 + w * 8 + rl;
            GLL(A + (size_t)row * lda + kk + gu * 8, As + (q * 32 + w * 8) * 64);
            GLL(B + (size_t)row * ldb + kk + gu * 8, Bs + (q * 32 + w * 8) * 64);
        }
        __syncthreads();

        const int wr = w >> 1, wc = w & 1;
        #pragma unroll
        for (int ks = 0; ks < 2; ++ks) {
            const int p = (ks * 4 + l4) ^ l7;
            bf16x8 af[4], bfr[4];
            #pragma unroll
            for (int m = 0; m < 4; ++m)
                af[m] = *(const bf16x8*)(As + (wr * 64 + m * 16 + l15) * 64 + p * 8);
            #pragma unroll
            for (int nb = 0; nb < 4; ++nb)
                bfr[nb] = *(const bf16x8*)(Bs + (wc * 64 + nb * 16 + l15) * 64 + p * 8);
            #pragma unroll
            for (int m = 0; m < 4; ++m)
                #pragma unroll
                for (int nb = 0; nb < 4; ++nb)
                    acc[m][nb] = __builtin_amdgcn_mfma_f32_16x16x32_bf16(af[m], bfr[nb], acc[m][nb], 0, 0, 0);
        }
    }
}

// ---------------- K1v GEMM: vl0[2048][512] = xB @ Wv^T + value_b -------------------
__global__ __launch_bounds__(256)
void k1v(const hbf* __restrict__ xB, const hbf* __restrict__ Wv,
         const float* __restrict__ value_b, float* __restrict__ vl0)
{
    __shared__ __align__(16) short As[128 * 64];
    __shared__ __align__(16) short Bs[128 * 64];
    const int m0 = (blockIdx.x >> 2) * 128;
    const int c0 = (blockIdx.x & 3) * 128;

    const hbf* A = xB + (size_t)m0 * INDIM;
    const hbf* B = Wv + (size_t)c0 * INDIM;

    f32x4 acc[4][4];
    f32x4 zz = {0.0f, 0.0f, 0.0f, 0.0f};
    #pragma unroll
    for (int m = 0; m < 4; ++m)
        #pragma unroll
        for (int nb = 0; nb < 4; ++nb) acc[m][nb] = zz;

    gemm_core64(A, INDIM, B, INDIM, INDIM, As, Bs, acc);

    const int t = threadIdx.x;
    const int w = t >> 6, lane = t & 63, l15 = lane & 15, l4 = lane >> 4;
    const int wr = w >> 1, wc = w & 1;
    #pragma unroll
    for (int nb = 0; nb < 4; ++nb) {
        int col = c0 + wc * 64 + nb * 16 + l15;
        float bias = (col < VAL) ? value_b[col] : 0.0f;
        #pragma unroll
        for (int m = 0; m < 4; ++m)
            #pragma unroll
            for (int j = 0; j < 4; ++j) {
                int row = m0 + wr * 64 + m * 16 + l4 * 4 + j;
                vl0[(size_t)row * 512 + col] = acc[m][nb][j] + bias;
            }
    }
}

// ---------------- K2 GEMM: g[b][n][1024] = A2[b][n][:] @ W2[n][c][:]^T -------------
__global__ __launch_bounds__(256)
void k2g(const hbf* __restrict__ A2, const hbf* __restrict__ W2, hbf* __restrict__ g)
{
    __shared__ __align__(16) short As[128 * 64];
    __shared__ __align__(16) short Bs[128 * 64];
    const int id = blockIdx.x;
    const int xcd = id & 7, idx = id >> 3;
    const int n  = xcd + ((idx >> 7) << 3);
    const int rem = idx & 127;
    const int m0 = (rem >> 3) * 128;
    const int c0 = (rem & 7) * 128;

    const hbf* A = A2 + (size_t)n * K2P + (size_t)m0 * (NRIM * K2P);
    const hbf* B = W2 + (size_t)n * (1024 * K2P) + (size_t)c0 * K2P;

    f32x4 acc[4][4];
    f32x4 zz = {0.0f, 0.0f, 0.0f, 0.0f};
    #pragma unroll
    for (int m = 0; m < 4; ++m)
        #pragma unroll
        for (int nb = 0; nb < 4; ++nb) acc[m][nb] = zz;

    gemm_core64(A, NRIM * K2P, B, K2P, K2P, As, Bs, acc);

    const int t = threadIdx.x;
    const int w = t >> 6, lane = t & 63, l15 = lane & 15, l4 = lane >> 4;
    const int wr = w >> 1, wc = w & 1;
    #pragma unroll
    for (int m = 0; m < 4; ++m)
        #pragma unroll
        for (int nb = 0; nb < 4; ++nb) {
            int col = c0 + wc * 64 + nb * 16 + l15;
            #pragma unroll
            for (int j = 0; j < 4; ++j) {
                int row = m0 + wr * 64 + m * 16 + l4 * 4 + j;
                g[((size_t)row * NRIM + n) * 1024 + col] = __float2bfloat16(acc[m][nb][j]);
            }
        }
}

// ---------------- GRU elementwise epilogue (hs from A2's bf16 copy) ----------------
__global__ __launch_bounds__(256)
void k_gru_ep(const hbf* __restrict__ g, const hbf* __restrict__ A2, hbf* __restrict__ hyB)
{
    const size_t row = blockIdx.x;
    const int t = threadIdx.x;
    const hbf* gr = g + row * 1024;
    float r  = __bfloat162float(gr[t]);
    float ig = __bfloat162float(gr[t + 256]);
    float xn = __bfloat162float(gr[t + 512]);
    float hn = __bfloat162float(gr[t + 768]);
    float reset = sigmoidf_(r);
    float inp   = sigmoidf_(ig);
    float newg  = tanhf(xn + reset * hn);
    float h     = __bfloat162float(A2[row * K2P + t]);
    hyB[row * HID + t] = __float2bfloat16(newg + inp * (h - newg));
}

// ---------------- K3 GEMM: qk[(b*16+n)][256], vT[b][h][d][m=n] = hy @ Wqkv^T -------
__global__ __launch_bounds__(256)
void k3g(const hbf* __restrict__ hyB, const hbf* __restrict__ Wqkv,
         hbf* __restrict__ qk, hbf* __restrict__ vT)
{
    __shared__ __align__(16) short As[128 * 64];
    __shared__ __align__(16) short Bs[128 * 64];
    const int id = blockIdx.x;
    const int xcd = id & 7, idx = id >> 3;          // idx in [0,320)
    const int n  = xcd + (idx / 160) * 8;
    const int rem = idx % 160;
    const int m0 = (rem / 10) * 128;                // batch-tile base
    const int c0 = (rem % 10) * 128;

    const hbf* A = hyB + (size_t)n * HID + (size_t)m0 * (NRIM * HID);
    const hbf* B = Wqkv + (size_t)n * (1280 * 256) + (size_t)c0 * 256;

    f32x4 acc[4][4];
    f32x4 zz = {0.0f, 0.0f, 0.0f, 0.0f};
    #pragma unroll
    for (int m = 0; m < 4; ++m)
        #pragma unroll
        for (int nb = 0; nb < 4; ++nb) acc[m][nb] = zz;

    gemm_core64(A, NRIM * HID, B, 256, 256, As, Bs, acc);

    const int t = threadIdx.x;
    const int w = t >> 6, lane = t & 63, l15 = lane & 15, l4 = lane >> 4;
    const int wr = w >> 1, wc = w & 1;
    #pragma unroll
    for (int m = 0; m < 4; ++m)
        #pragma unroll
        for (int nb = 0; nb < 4; ++nb) {
            int col = c0 + wc * 64 + nb * 16 + l15;
            int rb  = m0 + wr * 64 + m * 16 + l4 * 4;   // batch base for this lane
            if (col < 256) {
                // q,k: qk row = batch*16 + n
                #pragma unroll
                for (int j = 0; j < 4; ++j)
                    qk[((size_t)(rb + j) * NRIM + n) * 256 + col] = __float2bfloat16(acc[m][nb][j]);
            } else {
                // v -> transposed vT[b][h][d][m=n]
                int cc = col - 256, hh = cc >> 8, dd = cc & 255;
                #pragma unroll
                for (int j = 0; j < 4; ++j)
                    vT[(((size_t)(rb + j) * 4 + hh) * 256 + dd) * 16 + n] = __float2bfloat16(acc[m][nb][j]);
            }
        }
}

// ---------------- K4: attention, fully MFMA, one block per b, wave = head ----------
__global__ __launch_bounds__(256)
void k4_attn(const hbf* __restrict__ qk, const hbf* __restrict__ vT,
             const float* __restrict__ maskg, hbf* __restrict__ ctx)
{
    const int b = blockIdx.x;
    const int t = threadIdx.x;
    const int w = t >> 6, lane = t & 63;
    const int l15 = lane & 15, g = lane >> 4;

    // S^T = K @ Q^T : lane holds S[m=4g+j][n=l15]
    const hbf* qrow = qk + (size_t)(b * 16 + l15) * 256 + w * 32 + g * 8;
    bf16x8 qf = *(const bf16x8*)(qrow);
    bf16x8 kf = *(const bf16x8*)(qrow + 128);
    f32x4 s = {0.f, 0.f, 0.f, 0.f};
    s = __builtin_amdgcn_mfma_f32_16x16x32_bf16(kf, qf, s, 0, 0, 0);

    const float scale = 0.17677669529663687f;
    float v0 = s[0] * scale, v1 = s[1] * scale, v2 = s[2] * scale, v3 = s[3] * scale;
    float mx = fmaxf(fmaxf(v0, v1), fmaxf(v2, v3));
    mx = fmaxf(mx, __shfl_xor(mx, 16));
    mx = fmaxf(mx, __shfl_xor(mx, 32));
    float e0 = expf(v0 - mx), e1 = expf(v1 - mx), e2 = expf(v2 - mx), e3 = expf(v3 - mx);
    float sm = e0 + e1 + e2 + e3;
    sm += __shfl_xor(sm, 16);
    sm += __shfl_xor(sm, 32);
    float inv = maskg[b * NRIM + l15] / sm;   // row-mask * softmax-normalize

    // P^T regs -> B-fragment for PV mfma (lane n=l15 needs m=8g..8g+7; zero g>=2)
    unsigned u0 = packbf(e0 * inv, e1 * inv);
    unsigned u1 = packbf(e2 * inv, e3 * inv);
    int sl = l15 + (g << 5);
    unsigned f0 = __shfl((int)u0, sl);
    unsigned f1 = __shfl((int)u1, sl);
    unsigned f2 = __shfl((int)u0, sl + 16);
    unsigned f3 = __shfl((int)u1, sl + 16);
    if (lane >= 32) { f0 = 0; f1 = 0; f2 = 0; f3 = 0; }
    union { unsigned u[4]; bf16x8 v; } pf;
    pf.u[0] = f0; pf.u[1] = f1; pf.u[2] = f2; pf.u[3] = f3;

    // PV: D[d_sub=4g+j][n=l15] per 16-wide d chunk; A-frag = vT rows (d), k=m
    const hbf* vb = vT + ((size_t)(b * 4 + w) * 256 + l15) * 16 + (g & 1) * 8;
    hbf* crow = ctx + (size_t)(b * 16 + l15) * 1024 + w * 256 + g * 4;
    #pragma unroll
    for (int dc = 0; dc < 16; ++dc) {
        bf16x8 vf = *(const bf16x8*)(vb + dc * 256);
        f32x4 o = {0.f, 0.f, 0.f, 0.f};
        o = __builtin_amdgcn_mfma_f32_16x16x32_bf16(vf, pf.v, o, 0, 0, 0);
        unsigned lo = packbf(o[0], o[1]);
        unsigned hi = packbf(o[2], o[3]);
        *(uint2*)(crow + dc * 16) = make_uint2(lo, hi);
    }
}

// ---------------- K5 GEMM: out = mask ? ctx @ Wout^T + hy : hs ---------------------
__global__ __launch_bounds__(256)
void k5g(const hbf* __restrict__ ctx, const hbf* __restrict__ Wout,
         const hbf* __restrict__ hyB, const float* __restrict__ hs,
         const float* __restrict__ maskg, float* __restrict__ out)
{
    __shared__ __align__(16) short As[128 * 64];
    __shared__ __align__(16) short Bs[128 * 64];
    const int id = blockIdx.x;
    const int xcd = id & 7, idx = id >> 3;          // idx in [0,64)
    const int n  = xcd + ((idx >> 5) << 3);
    const int rem = idx & 31;
    const int m0 = (rem >> 1) * 128;
    const int c0 = (rem & 1) * 128;

    const hbf* A = ctx + (size_t)n * 1024 + (size_t)m0 * (NRIM * 1024);
    const hbf* B = Wout + (size_t)n * (256 * 1024) + (size_t)c0 * 1024;

    f32x4 acc[4][4];
    f32x4 zz = {0.0f, 0.0f, 0.0f, 0.0f};
    #pragma unroll
    for (int m = 0; m < 4; ++m)
        #pragma unroll
        for (int nb = 0; nb < 4; ++nb) acc[m][nb] = zz;

    gemm_core64(A, NRIM * 1024, B, 1024, 1024, As, Bs, acc);

    const int t = threadIdx.x;
    const int w = t >> 6, lane = t & 63, l15 = lane & 15, l4 = lane >> 4;
    const int wr = w >> 1, wc = w & 1;
    #pragma unroll
    for (int m = 0; m < 4; ++m)
        #pragma unroll
        for (int nb = 0; nb < 4; ++nb) {
            int col = c0 + wc * 64 + nb * 16 + l15;
            #pragma unroll
            for (int j = 0; j < 4; ++j) {
                int row = m0 + wr * 64 + m * 16 + l4 * 4 + j;
                size_t idx2 = ((size_t)row * NRIM + n) * HID + col;
                float mk = maskg[row * NRIM + n];
                out[idx2] = (mk > 0.5f) ? (acc[m][nb][j] + __bfloat162float(hyB[idx2]))
                                        : hs[idx2];
            }
        }
}

extern "C" void kernel_launch(void* const* d_in, const int* in_sizes, int n_in,
                              void* d_out, int out_size, void* d_ws, size_t ws_size,
                              hipStream_t stream) {
    const float* x       = (const float*)d_in[0];
    const float* hs      = (const float*)d_in[1];
    const float* option  = (const float*)d_in[2];
    const float* value_w = (const float*)d_in[3];
    const float* value_b = (const float*)d_in[4];
    const float* p_w     = (const float*)d_in[5];
    const float* p_b     = (const float*)d_in[6];
    const float* x2h_w   = (const float*)d_in[7];
    const float* h2h_w   = (const float*)d_in[8];
    const float* q_w     = (const float*)d_in[9];
    const float* k_w     = (const float*)d_in[10];
    const float* v_w     = (const float*)d_in[11];
    const float* out_w   = (const float*)d_in[12];
    float* out = (float*)d_out;

    char* ws = (char*)d_ws;
    // region0: A2 (46.1 MB) / ctx (67 MB) union  (A2 dead after k_gru_ep)
    hbf* A2   = (hbf*)(ws);
    hbf* ctx  = (hbf*)(ws);
    size_t off = 67108864;
    // region1: g (67 MB) / (qk 16.8 MB + vT 67 MB) union (g dead after k_gru_ep)
    hbf* g    = (hbf*)(ws + off);
    hbf* qk   = (hbf*)(ws + off);
    hbf* vT   = (hbf*)(ws + off + 16777216);
    off += 83886080;
    hbf* W2   = (hbf*)(ws + off); off += 23068672;   // [16][1024][704]
    hbf* Wqkv = (hbf*)(ws + off); off += 10485760;   // [16][1280][256]
    hbf* Wout = (hbf*)(ws + off); off += 8388608;    // [16][256][1024]
    hbf* hyB  = (hbf*)(ws + off); off += 16777216;   // [32768][256]
    float* vl0   = (float*)(ws + off); off += 4194304;   // [2048][512] f32
    hbf* xB   = (hbf*)(ws + off); off += 2097152;    // [2048][512] bf16
    hbf* Wv   = (hbf*)(ws + off); off += 524288;     // [512][512] bf16
    float* p0g   = (float*)(ws + off); off += 131072;
    float* maskg = (float*)(ws + off); off += 131072;

    // --- weight conversion (transpose to [cols][K], bf16) ---
    k_zero<<<dim3(5632), dim3(256), 0, stream>>>(W2, 1441792L);
    k_zero<<<dim3(128), dim3(256), 0, stream>>>(Wv, 32768L);
    t_conv<<<dim3(24, 8, 16), dim3(256), 0, stream>>>(h2h_w, W2, 256, 768,
            196608L, 720896L, K2P, 0, 0, 1);
    t_conv<<<dim3(24, 13, 16), dim3(256), 0, stream>>>(x2h_w, W2, 400, 768,
            307200L, 720896L, K2P, 256, 0, 0);
    t_conv<<<dim3(4, 8, 16), dim3(256), 0, stream>>>(q_w, Wqkv, 256, 128,
            32768L, 327680L, 256, 0, 0, 0);
    t_conv<<<dim3(4, 8, 16), dim3(256), 0, stream>>>(k_w, Wqkv, 256, 128,
            32768L, 327680L, 256, 0, 128, 0);
    t_conv<<<dim3(32, 8, 16), dim3(256), 0, stream>>>(v_w, Wqkv, 256, 1024,
            262144L, 327680L, 256, 0, 256, 0);
    t_conv<<<dim3(8, 32, 16), dim3(256), 0, stream>>>(out_w, Wout, 1024, 256,
            262144L, 262144L, 1024, 0, 0, 0);
    t_conv<<<dim3(13, 16, 1), dim3(256), 0, stream>>>(value_w, Wv, 512, 400,
            0L, 0L, 512, 0, 0, 0);

    // --- gating + value GEMM + inputs ---
    k1s<<<dim3(BATCH / 16), dim3(256), 0, stream>>>(option, p_w, p_b, p0g, maskg);
    k_xb<<<dim3(1024), dim3(256), 0, stream>>>(x, xB);
    k1v<<<dim3(64), dim3(256), 0, stream>>>(xB, Wv, value_b, vl0);
    k1b_a2<<<dim3(BATCH), dim3(256), 0, stream>>>(hs, vl0, p0g, maskg, value_b, A2);

    // --- GRU gates GEMM + elementwise ---
    k2g<<<dim3(2048), dim3(256), 0, stream>>>(A2, W2, g);
    k_gru_ep<<<dim3(BATCH * NRIM), dim3(256), 0, stream>>>(g, A2, hyB);

    // --- QKV GEMM (q,k -> qk buffer; v -> transposed vT) ---
    k3g<<<dim3(2560), dim3(256), 0, stream>>>(hyB, Wqkv, qk, vT);

    // --- attention (pure MFMA) ---
    k4_attn<<<dim3(BATCH), dim3(256), 0, stream>>>(qk, vT, maskg, ctx);

    // --- output projection GEMM (fused mask/residual) ---
    k5g<<<dim3(512), dim3(256), 0, stream>>>(ctx, Wout, hyB, hs, maskg, out);
}

// Round 7
// 299.388 us; speedup vs baseline: 1.6579x; 1.6579x over previous
//
#include <hip/hip_runtime.h>
#include <hip/hip_bf16.h>
#include <math.h>

#define BATCH 2048
#define INDIM 512
#define HID   256
#define NRIM  16
#define VAL   400
#define ONUM  8
#define CH    4
#define CK    32
#define CV    256
#define KACT  8
#define K2P   704   // GRU K padded to multiple of 64 (672 -> 704)

typedef __hip_bfloat16 hbf;
typedef __attribute__((ext_vector_type(8))) __bf16 bf16x8;
typedef __attribute__((ext_vector_type(4))) float f32x4;

__device__ __forceinline__ float sigmoidf_(float x) { return 1.0f / (1.0f + expf(-x)); }

__device__ __forceinline__ unsigned packbf(float a, float b) {
    hbf ha = __float2bfloat16(a), hb = __float2bfloat16(b);
    unsigned short ua, ub;
    __builtin_memcpy(&ua, &ha, 2);
    __builtin_memcpy(&ub, &hb, 2);
    return ((unsigned)ub << 16) | ua;
}

#define GLL(g, l) __builtin_amdgcn_global_load_lds(                                   \
    (const __attribute__((address_space(1))) void*)(g),                               \
    (__attribute__((address_space(3))) void*)(l), 16, 0, 0)

// ---------------- K1s: scores, top-k mask, softmax p0 (16 batches / block) ---------
__global__ __launch_bounds__(256)
void k1s(const float* __restrict__ option, const float* __restrict__ p_w,
         const float* __restrict__ p_b, float* __restrict__ p0g, float* __restrict__ maskg)
{
    const int t  = threadIdx.x;
    const int bb = t >> 4, n = t & 15;
    const int b  = blockIdx.x * 16 + bb;
    __shared__ float sc[16][17];

    float s0 = p_b[n], s1 = 0.0f;
    #pragma unroll
    for (int o = 0; o < ONUM; ++o) {
        s0 = fmaf(option[(b * 2 + 0) * ONUM + o], p_w[o * NRIM + n], s0);
        s1 = fmaf(option[(b * 2 + 1) * ONUM + o], p_w[o * NRIM + n], s1);
    }
    sc[bb][n] = s0;
    __syncthreads();

    int rank = 0;
    #pragma unroll
    for (int m = 0; m < NRIM; ++m) {
        float sm = sc[bb][m];
        if (sm > s0 || (sm == s0 && m < n)) rank++;
    }
    float mk = (rank < KACT) ? 1.0f : 0.0f;
    float mx = fmaxf(s0, s1);
    float e0 = expf(s0 - mx), e1 = expf(s1 - mx);
    p0g[b * NRIM + n]   = e0 / (e0 + e1);
    maskg[b * NRIM + n] = mk;
}

// ---------------- x -> bf16 --------------------------------------------------------
__global__ __launch_bounds__(256)
void k_xb(const float* __restrict__ x, hbf* __restrict__ xB)
{
    const int i = blockIdx.x * 256 + threadIdx.x;
    float4 v = ((const float4*)x)[i];
    unsigned lo = packbf(v.x, v.y), hi = packbf(v.z, v.w);
    *(uint2*)(xB + (size_t)i * 4) = make_uint2(lo, hi);
}

// ---------------- K1b: A2[b][n][K2P] = [ bf16(hs) | masked inputs | 0 pad ] --------
__global__ __launch_bounds__(256)
void k1b_a2(const float* __restrict__ hs, const float* __restrict__ vl0,
            const float* __restrict__ p0g, const float* __restrict__ maskg,
            const float* __restrict__ value_b, hbf* __restrict__ A2)
{
    const int b = blockIdx.x;
    const int t = threadIdx.x;
    __shared__ float vS[VAL], bS[VAL];
    if (t < 100) {
        ((float4*)vS)[t] = ((const float4*)(vl0 + (size_t)b * 512))[t];
        ((float4*)bS)[t] = ((const float4*)value_b)[t];
    }
    __syncthreads();

    for (int n = 0; n < NRIM; ++n) {
        size_t ro = ((size_t)b * NRIM + n) * K2P;
        float p0 = p0g[b * NRIM + n], mk = maskg[b * NRIM + n];
        if (t < 128) {
            float2 hv = ((const float2*)(hs + ((size_t)b * NRIM + n) * HID))[t];
            ((unsigned*)(A2 + ro))[t] = packbf(hv.x, hv.y);
        } else if (t < 152) {
            ((unsigned*)(A2 + ro + 656))[t - 128] = 0;
        }
        if (t < 200) {
            float a0 = mk * (p0 * vS[2 * t]     + (1.0f - p0) * bS[2 * t]);
            float a1 = mk * (p0 * vS[2 * t + 1] + (1.0f - p0) * bS[2 * t + 1]);
            ((unsigned*)(A2 + ro + 256))[t] = packbf(a0, a1);
        }
    }
}

// ---------------- zero fill (bf16, nelem8 = count of 16B chunks) -------------------
__global__ __launch_bounds__(256)
void k_zero(hbf* __restrict__ p, long nelem8)
{
    long i = (long)blockIdx.x * 256 + threadIdx.x;
    if (i < nelem8) {
        uint4 z; z.x = 0; z.y = 0; z.z = 0; z.w = 0;
        ((uint4*)p)[i] = z;
    }
}

// ---------------- transpose+convert: dst[n][coff+cmap(c)][koff+k] = src[n][k][c] ---
__global__ __launch_bounds__(256)
void t_conv(const float* __restrict__ src, hbf* __restrict__ dst,
            int K, int C, long s_nstride, long d_nstride, int dstride,
            int koff, int coff, int cmode)
{
    const int n  = blockIdx.z;
    const int c0 = blockIdx.x * 32, k0 = blockIdx.y * 32;
    const int tx = threadIdx.x & 31, ty = threadIdx.x >> 5;
    __shared__ float tile[32][33];
    const float* s = src + (size_t)n * s_nstride;
    #pragma unroll
    for (int i = 0; i < 4; ++i) {
        int k = k0 + ty + i * 8, c = c0 + tx;
        tile[ty + i * 8][tx] = (k < K && c < C) ? s[(size_t)k * C + c] : 0.0f;
    }
    __syncthreads();
    hbf* d = dst + (size_t)n * d_nstride;
    #pragma unroll
    for (int i = 0; i < 4; ++i) {
        int c = c0 + ty + i * 8, k = k0 + tx;
        if (c < C && k < K) {
            int cc = coff + (cmode ? (c < 512 ? c : c + 256) : c);
            d[(size_t)cc * dstride + koff + k] = __float2bfloat16(tile[tx][ty + i * 8]);
        }
    }
}

// ------ MFMA GEMM core: BK=64, swizzled LDS (pre-swizzled global src, rule #21) ----
__device__ __forceinline__ void gemm_core64(const hbf* __restrict__ A, long lda,
                                            const hbf* __restrict__ B, long ldb,
                                            int K, short* As, short* Bs, f32x4 acc[4][4])
{
    const int t = threadIdx.x;
    const int w = t >> 6, lane = t & 63;
    const int l15 = lane & 15, l4 = lane >> 4;
    const int rl = lane >> 3;
    const int gu = (lane & 7) ^ rl;
    const int l7 = l15 & 7;

    for (int kk = 0; kk < K; kk += 64) {
        __syncthreads();
        #pragma unroll
        for (int q = 0; q < 4; ++q) {
            int row = q * 32 + w * 8 + rl;
            GLL(A + (size_t)row * lda + kk + gu * 8, As + (q * 32 + w * 8) * 64);
            GLL(B + (size_t)row * ldb + kk + gu * 8, Bs + (q * 32 + w * 8) * 64);
        }
        __syncthreads();

        const int wr = w >> 1, wc = w & 1;
        #pragma unroll
        for (int ks = 0; ks < 2; ++ks) {
            const int p = (ks * 4 + l4) ^ l7;
            bf16x8 af[4], bfr[4];
            #pragma unroll
            for (int m = 0; m < 4; ++m)
                af[m] = *(const bf16x8*)(As + (wr * 64 + m * 16 + l15) * 64 + p * 8);
            #pragma unroll
            for (int nb = 0; nb < 4; ++nb)
                bfr[nb] = *(const bf16x8*)(Bs + (wc * 64 + nb * 16 + l15) * 64 + p * 8);
            #pragma unroll
            for (int m = 0; m < 4; ++m)
                #pragma unroll
                for (int nb = 0; nb < 4; ++nb)
                    acc[m][nb] = __builtin_amdgcn_mfma_f32_16x16x32_bf16(af[m], bfr[nb], acc[m][nb], 0, 0, 0);
        }
    }
}

// ---------------- K1v GEMM: vl0[2048][512] = xB @ Wv^T + value_b -------------------
__global__ __launch_bounds__(256)
void k1v(const hbf* __restrict__ xB, const hbf* __restrict__ Wv,
         const float* __restrict__ value_b, float* __restrict__ vl0)
{
    __shared__ __align__(16) short As[128 * 64];
    __shared__ __align__(16) short Bs[128 * 64];
    const int m0 = (blockIdx.x >> 2) * 128;
    const int c0 = (blockIdx.x & 3) * 128;

    const hbf* A = xB + (size_t)m0 * INDIM;
    const hbf* B = Wv + (size_t)c0 * INDIM;

    f32x4 acc[4][4];
    f32x4 zz = {0.0f, 0.0f, 0.0f, 0.0f};
    #pragma unroll
    for (int m = 0; m < 4; ++m)
        #pragma unroll
        for (int nb = 0; nb < 4; ++nb) acc[m][nb] = zz;

    gemm_core64(A, INDIM, B, INDIM, INDIM, As, Bs, acc);

    const int t = threadIdx.x;
    const int w = t >> 6, lane = t & 63, l15 = lane & 15, l4 = lane >> 4;
    const int wr = w >> 1, wc = w & 1;
    #pragma unroll
    for (int nb = 0; nb < 4; ++nb) {
        int col = c0 + wc * 64 + nb * 16 + l15;
        float bias = (col < VAL) ? value_b[col] : 0.0f;
        #pragma unroll
        for (int m = 0; m < 4; ++m)
            #pragma unroll
            for (int j = 0; j < 4; ++j) {
                int row = m0 + wr * 64 + m * 16 + l4 * 4 + j;
                vl0[(size_t)row * 512 + col] = acc[m][nb][j] + bias;
            }
    }
}

// ---------------- K2 GEMM: g[b][n][1024] = A2[b][n][:] @ W2[n][c][:]^T -------------
__global__ __launch_bounds__(256)
void k2g(const hbf* __restrict__ A2, const hbf* __restrict__ W2, hbf* __restrict__ g)
{
    __shared__ __align__(16) short As[128 * 64];
    __shared__ __align__(16) short Bs[128 * 64];
    const int id = blockIdx.x;
    const int xcd = id & 7, idx = id >> 3;
    const int n  = xcd + ((idx >> 7) << 3);
    const int rem = idx & 127;
    const int m0 = (rem >> 3) * 128;
    const int c0 = (rem & 7) * 128;

    const hbf* A = A2 + (size_t)n * K2P + (size_t)m0 * (NRIM * K2P);
    const hbf* B = W2 + (size_t)n * (1024 * K2P) + (size_t)c0 * K2P;

    f32x4 acc[4][4];
    f32x4 zz = {0.0f, 0.0f, 0.0f, 0.0f};
    #pragma unroll
    for (int m = 0; m < 4; ++m)
        #pragma unroll
        for (int nb = 0; nb < 4; ++nb) acc[m][nb] = zz;

    gemm_core64(A, NRIM * K2P, B, K2P, K2P, As, Bs, acc);

    const int t = threadIdx.x;
    const int w = t >> 6, lane = t & 63, l15 = lane & 15, l4 = lane >> 4;
    const int wr = w >> 1, wc = w & 1;
    #pragma unroll
    for (int m = 0; m < 4; ++m)
        #pragma unroll
        for (int nb = 0; nb < 4; ++nb) {
            int col = c0 + wc * 64 + nb * 16 + l15;
            #pragma unroll
            for (int j = 0; j < 4; ++j) {
                int row = m0 + wr * 64 + m * 16 + l4 * 4 + j;
                g[((size_t)row * NRIM + n) * 1024 + col] = __float2bfloat16(acc[m][nb][j]);
            }
        }
}

// ---------------- GRU elementwise epilogue (hs from A2's bf16 copy) ----------------
__global__ __launch_bounds__(256)
void k_gru_ep(const hbf* __restrict__ g, const hbf* __restrict__ A2, hbf* __restrict__ hyB)
{
    const size_t row = blockIdx.x;
    const int t = threadIdx.x;
    const hbf* gr = g + row * 1024;
    float r  = __bfloat162float(gr[t]);
    float ig = __bfloat162float(gr[t + 256]);
    float xn = __bfloat162float(gr[t + 512]);
    float hn = __bfloat162float(gr[t + 768]);
    float reset = sigmoidf_(r);
    float inp   = sigmoidf_(ig);
    float newg  = tanhf(xn + reset * hn);
    float h     = __bfloat162float(A2[row * K2P + t]);
    hyB[row * HID + t] = __float2bfloat16(newg + inp * (h - newg));
}

// ---------------- K3 GEMM: qkv[(b*16+n)][1280] = hy @ Wqkv^T (coalesced) -----------
__global__ __launch_bounds__(256)
void k3g(const hbf* __restrict__ hyB, const hbf* __restrict__ Wqkv, hbf* __restrict__ qkv)
{
    __shared__ __align__(16) short As[128 * 64];
    __shared__ __align__(16) short Bs[128 * 64];
    const int id = blockIdx.x;
    const int xcd = id & 7, idx = id >> 3;          // idx in [0,320)
    const int n  = xcd + (idx / 160) * 8;
    const int rem = idx % 160;
    const int m0 = (rem / 10) * 128;                // batch-tile base
    const int c0 = (rem % 10) * 128;

    const hbf* A = hyB + (size_t)n * HID + (size_t)m0 * (NRIM * HID);
    const hbf* B = Wqkv + (size_t)n * (1280 * 256) + (size_t)c0 * 256;

    f32x4 acc[4][4];
    f32x4 zz = {0.0f, 0.0f, 0.0f, 0.0f};
    #pragma unroll
    for (int m = 0; m < 4; ++m)
        #pragma unroll
        for (int nb = 0; nb < 4; ++nb) acc[m][nb] = zz;

    gemm_core64(A, NRIM * HID, B, 256, 256, As, Bs, acc);

    const int t = threadIdx.x;
    const int w = t >> 6, lane = t & 63, l15 = lane & 15, l4 = lane >> 4;
    const int wr = w >> 1, wc = w & 1;
    #pragma unroll
    for (int m = 0; m < 4; ++m)
        #pragma unroll
        for (int nb = 0; nb < 4; ++nb) {
            int col = c0 + wc * 64 + nb * 16 + l15;
            int rb  = m0 + wr * 64 + m * 16 + l4 * 4;   // batch base for this lane
            #pragma unroll
            for (int j = 0; j < 4; ++j)
                qkv[((size_t)(rb + j) * 16 + n) * 1280 + col] = __float2bfloat16(acc[m][nb][j]);
        }
}

// ---------------- K4: attention, MFMA + LDS V-transpose, block per b ---------------
__global__ __launch_bounds__(256)
void k4_attn(const hbf* __restrict__ qkv, const float* __restrict__ maskg,
             hbf* __restrict__ ctx)
{
    const int b = blockIdx.x;
    const int t = threadIdx.x;
    const int w = t >> 6, lane = t & 63;
    const int l15 = lane & 15, g = lane >> 4;

    __shared__ hbf vS[16 * 1024];   // V[m][h*256+d], 32KB

    // stage V coalesced: thread (r=t>>4, c=t&15) copies 8x16B of row r
    {
        const int r = t >> 4, c = t & 15;
        const uint4* src = (const uint4*)(qkv + (size_t)(b * 16 + r) * 1280 + 256);
        uint4* dst = (uint4*)(vS + r * 1024);
        #pragma unroll
        for (int i = 0; i < 8; ++i) dst[c + i * 16] = src[c + i * 16];
    }

    // S^T = K @ Q^T : lane holds S[m=4g+j][n=l15]
    const hbf* qrow = qkv + (size_t)(b * 16 + l15) * 1280 + w * 32 + g * 8;
    bf16x8 qf = *(const bf16x8*)(qrow);
    bf16x8 kf = *(const bf16x8*)(qrow + 128);
    f32x4 s = {0.f, 0.f, 0.f, 0.f};
    s = __builtin_amdgcn_mfma_f32_16x16x32_bf16(kf, qf, s, 0, 0, 0);

    const float scale = 0.17677669529663687f;
    float v0 = s[0] * scale, v1 = s[1] * scale, v2 = s[2] * scale, v3 = s[3] * scale;
    float mx = fmaxf(fmaxf(v0, v1), fmaxf(v2, v3));
    mx = fmaxf(mx, __shfl_xor(mx, 16));
    mx = fmaxf(mx, __shfl_xor(mx, 32));
    float e0 = expf(v0 - mx), e1 = expf(v1 - mx), e2 = expf(v2 - mx), e3 = expf(v3 - mx);
    float sm = e0 + e1 + e2 + e3;
    sm += __shfl_xor(sm, 16);
    sm += __shfl_xor(sm, 32);
    float inv = maskg[b * NRIM + l15] / sm;   // row-mask * softmax-normalize

    // P^T regs -> B-fragment for PV mfma (lane n=l15 needs m=8g..8g+7; zero g>=2)
    unsigned u0 = packbf(e0 * inv, e1 * inv);
    unsigned u1 = packbf(e2 * inv, e3 * inv);
    int sl = l15 + (g << 5);
    unsigned f0 = __shfl((int)u0, sl);
    unsigned f1 = __shfl((int)u1, sl);
    unsigned f2 = __shfl((int)u0, sl + 16);
    unsigned f3 = __shfl((int)u1, sl + 16);
    if (lane >= 32) { f0 = 0; f1 = 0; f2 = 0; f3 = 0; }
    union { unsigned u[4]; bf16x8 v; } pf;
    pf.u[0] = f0; pf.u[1] = f1; pf.u[2] = f2; pf.u[3] = f3;

    __syncthreads();

    // PV: A-frag lane (row=l15 -> d_local, g -> m-group) from LDS column reads
    const unsigned short* vsu = (const unsigned short*)vS;
    const int vbase = (8 * (g & 1)) * 1024 + w * 256 + l15;   // + e*1024 + dc*16
    hbf* crow = ctx + (size_t)(b * 16 + l15) * 1024 + w * 256 + g * 4;
    #pragma unroll
    for (int dc = 0; dc < 16; ++dc) {
        union { unsigned short u[8]; bf16x8 v; } vf;
        #pragma unroll
        for (int e = 0; e < 8; ++e)
            vf.u[e] = vsu[vbase + e * 1024 + dc * 16];
        f32x4 o = {0.f, 0.f, 0.f, 0.f};
        o = __builtin_amdgcn_mfma_f32_16x16x32_bf16(vf.v, pf.v, o, 0, 0, 0);
        unsigned lo = packbf(o[0], o[1]);
        unsigned hi = packbf(o[2], o[3]);
        *(uint2*)(crow + dc * 16) = make_uint2(lo, hi);
    }
}

// ---------------- K5 GEMM: out = mask ? ctx @ Wout^T + hy : hs ---------------------
__global__ __launch_bounds__(256)
void k5g(const hbf* __restrict__ ctx, const hbf* __restrict__ Wout,
         const hbf* __restrict__ hyB, const float* __restrict__ hs,
         const float* __restrict__ maskg, float* __restrict__ out)
{
    __shared__ __align__(16) short As[128 * 64];
    __shared__ __align__(16) short Bs[128 * 64];
    const int id = blockIdx.x;
    const int xcd = id & 7, idx = id >> 3;          // idx in [0,64)
    const int n  = xcd + ((idx >> 5) << 3);
    const int rem = idx & 31;
    const int m0 = (rem >> 1) * 128;
    const int c0 = (rem & 1) * 128;

    const hbf* A = ctx + (size_t)n * 1024 + (size_t)m0 * (NRIM * 1024);
    const hbf* B = Wout + (size_t)n * (256 * 1024) + (size_t)c0 * 1024;

    f32x4 acc[4][4];
    f32x4 zz = {0.0f, 0.0f, 0.0f, 0.0f};
    #pragma unroll
    for (int m = 0; m < 4; ++m)
        #pragma unroll
        for (int nb = 0; nb < 4; ++nb) acc[m][nb] = zz;

    gemm_core64(A, NRIM * 1024, B, 1024, 1024, As, Bs, acc);

    const int t = threadIdx.x;
    const int w = t >> 6, lane = t & 63, l15 = lane & 15, l4 = lane >> 4;
    const int wr = w >> 1, wc = w & 1;
    #pragma unroll
    for (int m = 0; m < 4; ++m)
        #pragma unroll
        for (int nb = 0; nb < 4; ++nb) {
            int col = c0 + wc * 64 + nb * 16 + l15;
            #pragma unroll
            for (int j = 0; j < 4; ++j) {
                int row = m0 + wr * 64 + m * 16 + l4 * 4 + j;
                size_t idx2 = ((size_t)row * NRIM + n) * HID + col;
                float mk = maskg[row * NRIM + n];
                out[idx2] = (mk > 0.5f) ? (acc[m][nb][j] + __bfloat162float(hyB[idx2]))
                                        : hs[idx2];
            }
        }
}

extern "C" void kernel_launch(void* const* d_in, const int* in_sizes, int n_in,
                              void* d_out, int out_size, void* d_ws, size_t ws_size,
                              hipStream_t stream) {
    const float* x       = (const float*)d_in[0];
    const float* hs      = (const float*)d_in[1];
    const float* option  = (const float*)d_in[2];
    const float* value_w = (const float*)d_in[3];
    const float* value_b = (const float*)d_in[4];
    const float* p_w     = (const float*)d_in[5];
    const float* p_b     = (const float*)d_in[6];
    const float* x2h_w   = (const float*)d_in[7];
    const float* h2h_w   = (const float*)d_in[8];
    const float* q_w     = (const float*)d_in[9];
    const float* k_w     = (const float*)d_in[10];
    const float* v_w     = (const float*)d_in[11];
    const float* out_w   = (const float*)d_in[12];
    float* out = (float*)d_out;

    char* ws = (char*)d_ws;
    // region0: A2 (46.1 MB) / ctx (67 MB) union  (A2 dead after k_gru_ep)
    hbf* A2   = (hbf*)(ws);
    hbf* ctx  = (hbf*)(ws);
    size_t off = 67108864;
    // region1: g (67 MB) / qkv (84 MB) union (g dead after k_gru_ep)
    hbf* g    = (hbf*)(ws + off);
    hbf* qkv  = (hbf*)(ws + off);
    off += 83886080;
    hbf* W2   = (hbf*)(ws + off); off += 23068672;   // [16][1024][704]
    hbf* Wqkv = (hbf*)(ws + off); off += 10485760;   // [16][1280][256]
    hbf* Wout = (hbf*)(ws + off); off += 8388608;    // [16][256][1024]
    hbf* hyB  = (hbf*)(ws + off); off += 16777216;   // [32768][256]
    float* vl0   = (float*)(ws + off); off += 4194304;   // [2048][512] f32
    hbf* xB   = (hbf*)(ws + off); off += 2097152;    // [2048][512] bf16
    hbf* Wv   = (hbf*)(ws + off); off += 524288;     // [512][512] bf16
    float* p0g   = (float*)(ws + off); off += 131072;
    float* maskg = (float*)(ws + off); off += 131072;

    // --- weight conversion (transpose to [cols][K], bf16) ---
    k_zero<<<dim3(5632), dim3(256), 0, stream>>>(W2, 1441792L);
    k_zero<<<dim3(128), dim3(256), 0, stream>>>(Wv, 32768L);
    t_conv<<<dim3(24, 8, 16), dim3(256), 0, stream>>>(h2h_w, W2, 256, 768,
            196608L, 720896L, K2P, 0, 0, 1);
    t_conv<<<dim3(24, 13, 16), dim3(256), 0, stream>>>(x2h_w, W2, 400, 768,
            307200L, 720896L, K2P, 256, 0, 0);
    t_conv<<<dim3(4, 8, 16), dim3(256), 0, stream>>>(q_w, Wqkv, 256, 128,
            32768L, 327680L, 256, 0, 0, 0);
    t_conv<<<dim3(4, 8, 16), dim3(256), 0, stream>>>(k_w, Wqkv, 256, 128,
            32768L, 327680L, 256, 0, 128, 0);
    t_conv<<<dim3(32, 8, 16), dim3(256), 0, stream>>>(v_w, Wqkv, 256, 1024,
            262144L, 327680L, 256, 0, 256, 0);
    t_conv<<<dim3(8, 32, 16), dim3(256), 0, stream>>>(out_w, Wout, 1024, 256,
            262144L, 262144L, 1024, 0, 0, 0);
    t_conv<<<dim3(13, 16, 1), dim3(256), 0, stream>>>(value_w, Wv, 512, 400,
            0L, 0L, 512, 0, 0, 0);

    // --- gating + value GEMM + inputs ---
    k1s<<<dim3(BATCH / 16), dim3(256), 0, stream>>>(option, p_w, p_b, p0g, maskg);
    k_xb<<<dim3(1024), dim3(256), 0, stream>>>(x, xB);
    k1v<<<dim3(64), dim3(256), 0, stream>>>(xB, Wv, value_b, vl0);
    k1b_a2<<<dim3(BATCH), dim3(256), 0, stream>>>(hs, vl0, p0g, maskg, value_b, A2);

    // --- GRU gates GEMM + elementwise ---
    k2g<<<dim3(2048), dim3(256), 0, stream>>>(A2, W2, g);
    k_gru_ep<<<dim3(BATCH * NRIM), dim3(256), 0, stream>>>(g, A2, hyB);

    // --- QKV GEMM (coalesced single buffer) ---
    k3g<<<dim3(2560), dim3(256), 0, stream>>>(hyB, Wqkv, qkv);

    // --- attention (MFMA + LDS V-transpose) ---
    k4_attn<<<dim3(BATCH), dim3(256), 0, stream>>>(qkv, maskg, ctx);

    // --- output projection GEMM (fused mask/residual) ---
    k5g<<<dim3(512), dim3(256), 0, stream>>>(ctx, Wout, hyB, hs, maskg, out);
}

// Round 8
// 260.027 us; speedup vs baseline: 1.9088x; 1.1514x over previous
//
#include <hip/hip_runtime.h>
#include <hip/hip_bf16.h>
#include <math.h>

#define BATCH 2048
#define INDIM 512
#define HID   256
#define NRIM  16
#define VAL   400
#define ONUM  8
#define CH    4
#define CK    32
#define CV    256
#define KACT  8
#define K2P   704   // GRU K padded to multiple of 64 (672 -> 704)

typedef __hip_bfloat16 hbf;
typedef __attribute__((ext_vector_type(8))) __bf16 bf16x8;
typedef __attribute__((ext_vector_type(4))) float f32x4;

__device__ __forceinline__ float sigmoidf_(float x) { return 1.0f / (1.0f + expf(-x)); }

__device__ __forceinline__ unsigned packbf(float a, float b) {
    hbf ha = __float2bfloat16(a), hb = __float2bfloat16(b);
    unsigned short ua, ub;
    __builtin_memcpy(&ua, &ha, 2);
    __builtin_memcpy(&ub, &hb, 2);
    return ((unsigned)ub << 16) | ua;
}

#define GLL(g, l) __builtin_amdgcn_global_load_lds(                                   \
    (const __attribute__((address_space(1))) void*)(g),                               \
    (__attribute__((address_space(3))) void*)(l), 16, 0, 0)

// ---------------- transpose+convert body: dst[n][coff+cmap(c)][koff+k] = src[n][k][c]
__device__ __forceinline__ void t_conv_body(
    const float* __restrict__ src, hbf* __restrict__ dst,
    int K, int C, long s_ns, long d_ns, int dstride,
    int koff, int coff, int cmode, int bx, int by, int bz, float* tileS)
{
    const int c0 = bx * 32, k0 = by * 32;
    const int tx = threadIdx.x & 31, ty = threadIdx.x >> 5;
    float (*tile)[33] = (float(*)[33])tileS;
    const float* s = src + (size_t)bz * s_ns;
    #pragma unroll
    for (int i = 0; i < 4; ++i) {
        int k = k0 + ty + i * 8, c = c0 + tx;
        tile[ty + i * 8][tx] = (k < K && c < C) ? s[(size_t)k * C + c] : 0.0f;
    }
    __syncthreads();
    hbf* d = dst + (size_t)bz * d_ns;
    #pragma unroll
    for (int i = 0; i < 4; ++i) {
        int c = c0 + ty + i * 8, k = k0 + tx;
        if (c < C && k < K) {
            int cc = coff + (cmode ? (c < 512 ? c : c + 256) : c);
            d[(size_t)cc * dstride + koff + k] = __float2bfloat16(tile[tx][ty + i * 8]);
        }
    }
}

// ---------------- mega_prep: all weight transposes + targeted zeros + k1s + k_xb ---
// block ranges:
//  [0,3072)      h2h -> W2          (24x8x16)
//  [3072,8064)   x2h -> W2          (24x13x16)
//  [8064,8576)   q_w -> Wqkv        (4x8x16)
//  [8576,9088)   k_w -> Wqkv coff128(4x8x16)
//  [9088,13184)  v_w -> Wqkv coff256(32x8x16)
//  [13184,17280) out_w -> Wout      (8x32x16)
//  [17280,17488) value_w -> Wv      (13x16)
//  [17488,18672) Z1: W2 c[768,1024) k[256,704) + c[0,768) k[656,704)
//  [18672,18700) Z2: Wv c[400,512)
//  [18700,19212) Z3: W2 c[512,768) k[0,256)
//  [19212,19340) k1s
//  [19340,20364) k_xb
__global__ __launch_bounds__(256)
void mega_prep(const float* __restrict__ h2h_w, const float* __restrict__ x2h_w,
               const float* __restrict__ q_w, const float* __restrict__ k_w,
               const float* __restrict__ v_w, const float* __restrict__ out_w,
               const float* __restrict__ value_w, const float* __restrict__ option,
               const float* __restrict__ p_w, const float* __restrict__ p_b,
               const float* __restrict__ x,
               hbf* __restrict__ W2, hbf* __restrict__ Wqkv, hbf* __restrict__ Wout,
               hbf* __restrict__ Wv, float* __restrict__ p0g, float* __restrict__ maskg,
               hbf* __restrict__ xB)
{
    __shared__ float tileS[32 * 33];
    const int id = blockIdx.x;
    const int t  = threadIdx.x;

    if (id < 3072) {
        int l = id, bz = l / 192, rem = l % 192;
        t_conv_body(h2h_w, W2, 256, 768, 196608L, 720896L, K2P, 0, 0, 1,
                    rem % 24, rem / 24, bz, tileS);
    } else if (id < 8064) {
        int l = id - 3072, bz = l / 312, rem = l % 312;
        t_conv_body(x2h_w, W2, 400, 768, 307200L, 720896L, K2P, 256, 0, 0,
                    rem % 24, rem / 24, bz, tileS);
    } else if (id < 8576) {
        int l = id - 8064, bz = l / 32, rem = l % 32;
        t_conv_body(q_w, Wqkv, 256, 128, 32768L, 327680L, 256, 0, 0, 0,
                    rem % 4, rem / 4, bz, tileS);
    } else if (id < 9088) {
        int l = id - 8576, bz = l / 32, rem = l % 32;
        t_conv_body(k_w, Wqkv, 256, 128, 32768L, 327680L, 256, 0, 128, 0,
                    rem % 4, rem / 4, bz, tileS);
    } else if (id < 13184) {
        int l = id - 9088, bz = l / 256, rem = l % 256;
        t_conv_body(v_w, Wqkv, 256, 1024, 262144L, 327680L, 256, 0, 256, 0,
                    rem % 32, rem / 32, bz, tileS);
    } else if (id < 17280) {
        int l = id - 13184, bz = l / 256, rem = l % 256;
        t_conv_body(out_w, Wout, 1024, 256, 262144L, 262144L, 1024, 0, 0, 0,
                    rem % 8, rem / 8, bz, tileS);
    } else if (id < 17488) {
        int l = id - 17280;
        t_conv_body(value_w, Wv, 512, 400, 0L, 0L, 512, 0, 0, 0,
                    l % 13, l / 13, 0, tileS);
    } else if (id < 18672) {
        // Z1: per n, 18944 uint4 (74 blocks): (a) c[768,1024) units[32,88) = 14336
        //     (b) c[0,768) units[82,88) = 4608
        int l = id - 17488, n = l / 74, idx = (l % 74) * 256 + t;
        uint4 z; z.x = 0; z.y = 0; z.z = 0; z.w = 0;
        uint4* base = (uint4*)(W2 + (size_t)n * 720896);
        if (idx < 14336) {
            int c = 768 + idx / 56, u = 32 + idx % 56;
            base[(size_t)c * 88 + u] = z;
        } else {
            int i2 = idx - 14336;
            int c = i2 / 6, u = 82 + i2 % 6;
            base[(size_t)c * 88 + u] = z;
        }
    } else if (id < 18700) {
        // Z2: Wv c[400,512), 64 units/row -> 7168 uint4 (28 blocks)
        int idx = (id - 18672) * 256 + t;
        int c = 400 + idx / 64, u = idx % 64;
        uint4 z; z.x = 0; z.y = 0; z.z = 0; z.w = 0;
        ((uint4*)Wv)[(size_t)c * 64 + u] = z;
    } else if (id < 19212) {
        // Z3: W2 c[512,768) units[0,32) : 8192 uint4/n (32 blocks/n)
        int l = id - 18700, n = l / 32, idx = (l % 32) * 256 + t;
        int c = 512 + idx / 32, u = idx % 32;
        uint4 z; z.x = 0; z.y = 0; z.z = 0; z.w = 0;
        ((uint4*)(W2 + (size_t)n * 720896))[(size_t)c * 88 + u] = z;
    } else if (id < 19340) {
        // k1s: scores/top-k/softmax, 16 batches per block
        const int bb = t >> 4, n = t & 15;
        const int b  = (id - 19212) * 16 + bb;
        float (*sc)[17] = (float(*)[17])tileS;
        float s0 = p_b[n], s1 = 0.0f;
        #pragma unroll
        for (int o = 0; o < ONUM; ++o) {
            s0 = fmaf(option[(b * 2 + 0) * ONUM + o], p_w[o * NRIM + n], s0);
            s1 = fmaf(option[(b * 2 + 1) * ONUM + o], p_w[o * NRIM + n], s1);
        }
        sc[bb][n] = s0;
        __syncthreads();
        int rank = 0;
        #pragma unroll
        for (int m = 0; m < NRIM; ++m) {
            float sm = sc[bb][m];
            if (sm > s0 || (sm == s0 && m < n)) rank++;
        }
        float mk = (rank < KACT) ? 1.0f : 0.0f;
        float mx = fmaxf(s0, s1);
        float e0 = expf(s0 - mx), e1 = expf(s1 - mx);
        p0g[b * NRIM + n]   = e0 / (e0 + e1);
        maskg[b * NRIM + n] = mk;
    } else {
        // k_xb: x -> bf16
        int i = (id - 19340) * 256 + t;
        float4 v = ((const float4*)x)[i];
        unsigned lo = packbf(v.x, v.y), hi = packbf(v.z, v.w);
        *(uint2*)(xB + (size_t)i * 4) = make_uint2(lo, hi);
    }
}

// ---------------- K1b: A2[b][n][K2P] = [ bf16(hs) | masked inputs | 0 pad ] --------
__global__ __launch_bounds__(256)
void k1b_a2(const float* __restrict__ hs, const float* __restrict__ vl0,
            const float* __restrict__ p0g, const float* __restrict__ maskg,
            const float* __restrict__ value_b, hbf* __restrict__ A2)
{
    const int b = blockIdx.x;
    const int t = threadIdx.x;
    __shared__ float vS[VAL], bS[VAL];
    if (t < 100) {
        ((float4*)vS)[t] = ((const float4*)(vl0 + (size_t)b * 512))[t];
        ((float4*)bS)[t] = ((const float4*)value_b)[t];
    }
    __syncthreads();

    for (int n = 0; n < NRIM; ++n) {
        size_t ro = ((size_t)b * NRIM + n) * K2P;
        float p0 = p0g[b * NRIM + n], mk = maskg[b * NRIM + n];
        if (t < 128) {
            float2 hv = ((const float2*)(hs + ((size_t)b * NRIM + n) * HID))[t];
            ((unsigned*)(A2 + ro))[t] = packbf(hv.x, hv.y);
        } else if (t < 152) {
            ((unsigned*)(A2 + ro + 656))[t - 128] = 0;
        }
        if (t < 200) {
            float a0 = mk * (p0 * vS[2 * t]     + (1.0f - p0) * bS[2 * t]);
            float a1 = mk * (p0 * vS[2 * t + 1] + (1.0f - p0) * bS[2 * t + 1]);
            ((unsigned*)(A2 + ro + 256))[t] = packbf(a0, a1);
        }
    }
}

// ------ MFMA GEMM core: BK=64, swizzled LDS (pre-swizzled global src, rule #21) ----
__device__ __forceinline__ void gemm_core64(const hbf* __restrict__ A, long lda,
                                            const hbf* __restrict__ B, long ldb,
                                            int K, short* As, short* Bs, f32x4 acc[4][4])
{
    const int t = threadIdx.x;
    const int w = t >> 6, lane = t & 63;
    const int l15 = lane & 15, l4 = lane >> 4;
    const int rl = lane >> 3;
    const int gu = (lane & 7) ^ rl;
    const int l7 = l15 & 7;

    for (int kk = 0; kk < K; kk += 64) {
        __syncthreads();
        #pragma unroll
        for (int q = 0; q < 4; ++q) {
            int row = q * 32 + w * 8 + rl;
            GLL(A + (size_t)row * lda + kk + gu * 8, As + (q * 32 + w * 8) * 64);
            GLL(B + (size_t)row * ldb + kk + gu * 8, Bs + (q * 32 + w * 8) * 64);
        }
        __syncthreads();

        const int wr = w >> 1, wc = w & 1;
        #pragma unroll
        for (int ks = 0; ks < 2; ++ks) {
            const int p = (ks * 4 + l4) ^ l7;
            bf16x8 af[4], bfr[4];
            #pragma unroll
            for (int m = 0; m < 4; ++m)
                af[m] = *(const bf16x8*)(As + (wr * 64 + m * 16 + l15) * 64 + p * 8);
            #pragma unroll
            for (int nb = 0; nb < 4; ++nb)
                bfr[nb] = *(const bf16x8*)(Bs + (wc * 64 + nb * 16 + l15) * 64 + p * 8);
            #pragma unroll
            for (int m = 0; m < 4; ++m)
                #pragma unroll
                for (int nb = 0; nb < 4; ++nb)
                    acc[m][nb] = __builtin_amdgcn_mfma_f32_16x16x32_bf16(af[m], bfr[nb], acc[m][nb], 0, 0, 0);
        }
    }
}

// ---------------- K1v GEMM: vl0[2048][512] = xB @ Wv^T + value_b -------------------
__global__ __launch_bounds__(256)
void k1v(const hbf* __restrict__ xB, const hbf* __restrict__ Wv,
         const float* __restrict__ value_b, float* __restrict__ vl0)
{
    __shared__ __align__(16) short As[128 * 64];
    __shared__ __align__(16) short Bs[128 * 64];
    const int m0 = (blockIdx.x >> 2) * 128;
    const int c0 = (blockIdx.x & 3) * 128;

    const hbf* A = xB + (size_t)m0 * INDIM;
    const hbf* B = Wv + (size_t)c0 * INDIM;

    f32x4 acc[4][4];
    f32x4 zz = {0.0f, 0.0f, 0.0f, 0.0f};
    #pragma unroll
    for (int m = 0; m < 4; ++m)
        #pragma unroll
        for (int nb = 0; nb < 4; ++nb) acc[m][nb] = zz;

    gemm_core64(A, INDIM, B, INDIM, INDIM, As, Bs, acc);

    const int t = threadIdx.x;
    const int w = t >> 6, lane = t & 63, l15 = lane & 15, l4 = lane >> 4;
    const int wr = w >> 1, wc = w & 1;
    #pragma unroll
    for (int nb = 0; nb < 4; ++nb) {
        int col = c0 + wc * 64 + nb * 16 + l15;
        float bias = (col < VAL) ? value_b[col] : 0.0f;
        #pragma unroll
        for (int m = 0; m < 4; ++m)
            #pragma unroll
            for (int j = 0; j < 4; ++j) {
                int row = m0 + wr * 64 + m * 16 + l4 * 4 + j;
                vl0[(size_t)row * 512 + col] = acc[m][nb][j] + bias;
            }
    }
}

// ------ K2 GEMM + fused GRU: B-cols = 4 gates x 32 hidden cols; writes hyB directly
__global__ __launch_bounds__(256)
void k2g(const hbf* __restrict__ A2, const hbf* __restrict__ W2, hbf* __restrict__ hyB)
{
    __shared__ __align__(16) short As[128 * 64];
    __shared__ __align__(16) short Bs[128 * 64];
    const int id = blockIdx.x;
    const int xcd = id & 7, idx = id >> 3;
    const int n  = xcd + ((idx >> 7) << 3);
    const int rem = idx & 127;
    const int m0 = (rem >> 3) * 128;       // batch-tile base
    const int c0 = rem & 7;                // hidden-col strip [0,8): cols c0*32..c0*32+31

    const hbf* A = A2 + (size_t)n * K2P + (size_t)m0 * (NRIM * K2P);
    const hbf* Bb = W2 + (size_t)n * (1024 * K2P);

    const int t = threadIdx.x;
    const int w = t >> 6, lane = t & 63;
    const int l15 = lane & 15, l4 = lane >> 4;
    const int rl = lane >> 3;
    const int gu = (lane & 7) ^ rl;
    const int l7 = l15 & 7;
    const int wr = w >> 1, wc = w & 1;

    f32x4 acc[4][4];
    f32x4 zz = {0.0f, 0.0f, 0.0f, 0.0f};
    #pragma unroll
    for (int m = 0; m < 4; ++m)
        #pragma unroll
        for (int nb = 0; nb < 4; ++nb) acc[m][nb] = zz;

    for (int kk = 0; kk < K2P; kk += 64) {
        __syncthreads();
        #pragma unroll
        for (int q = 0; q < 4; ++q) {
            int row = q * 32 + w * 8 + rl;
            // B LDS row -> W2 row: gate=(row>>4)&3, cj=(row>>6)*16+(row&15)
            int wrow = ((row >> 4) & 3) * 256 + c0 * 32 + ((row >> 6) << 4) + (row & 15);
            GLL(A + (size_t)row * (NRIM * K2P) + kk + gu * 8, As + (q * 32 + w * 8) * 64);
            GLL(Bb + (size_t)wrow * K2P + kk + gu * 8, Bs + (q * 32 + w * 8) * 64);
        }
        __syncthreads();

        #pragma unroll
        for (int ks = 0; ks < 2; ++ks) {
            const int p = (ks * 4 + l4) ^ l7;
            bf16x8 af[4], bfr[4];
            #pragma unroll
            for (int m = 0; m < 4; ++m)
                af[m] = *(const bf16x8*)(As + (wr * 64 + m * 16 + l15) * 64 + p * 8);
            #pragma unroll
            for (int nb = 0; nb < 4; ++nb)
                bfr[nb] = *(const bf16x8*)(Bs + (wc * 64 + nb * 16 + l15) * 64 + p * 8);
            #pragma unroll
            for (int m = 0; m < 4; ++m)
                #pragma unroll
                for (int nb = 0; nb < 4; ++nb)
                    acc[m][nb] = __builtin_amdgcn_mfma_f32_16x16x32_bf16(af[m], bfr[nb], acc[m][nb], 0, 0, 0);
        }
    }

    // fused GRU epilogue: acc[m][gate][j]; col = c0*32 + wc*16 + l15
    const int col = c0 * 32 + wc * 16 + l15;
    #pragma unroll
    for (int m = 0; m < 4; ++m)
        #pragma unroll
        for (int j = 0; j < 4; ++j) {
            int row = m0 + wr * 64 + m * 16 + l4 * 4 + j;     // batch index
            size_t ridx = (size_t)row * NRIM + n;
            float r  = acc[m][0][j];
            float ig = acc[m][1][j];
            float xn = acc[m][2][j];
            float hn = acc[m][3][j];
            float reset = sigmoidf_(r);
            float inp   = sigmoidf_(ig);
            float newg  = tanhf(xn + reset * hn);
            float h     = __bfloat162float(A2[ridx * K2P + col]);
            hyB[ridx * HID + col] = __float2bfloat16(newg + inp * (h - newg));
        }
}

// ---------------- K3 GEMM: qkv[(b*16+n)][1280] = hy @ Wqkv^T (coalesced) -----------
__global__ __launch_bounds__(256)
void k3g(const hbf* __restrict__ hyB, const hbf* __restrict__ Wqkv, hbf* __restrict__ qkv)
{
    __shared__ __align__(16) short As[128 * 64];
    __shared__ __align__(16) short Bs[128 * 64];
    const int id = blockIdx.x;
    const int xcd = id & 7, idx = id >> 3;          // idx in [0,320)
    const int n  = xcd + (idx / 160) * 8;
    const int rem = idx % 160;
    const int m0 = (rem / 10) * 128;                // batch-tile base
    const int c0 = (rem % 10) * 128;

    const hbf* A = hyB + (size_t)n * HID + (size_t)m0 * (NRIM * HID);
    const hbf* B = Wqkv + (size_t)n * (1280 * 256) + (size_t)c0 * 256;

    f32x4 acc[4][4];
    f32x4 zz = {0.0f, 0.0f, 0.0f, 0.0f};
    #pragma unroll
    for (int m = 0; m < 4; ++m)
        #pragma unroll
        for (int nb = 0; nb < 4; ++nb) acc[m][nb] = zz;

    gemm_core64(A, NRIM * HID, B, 256, 256, As, Bs, acc);

    const int t = threadIdx.x;
    const int w = t >> 6, lane = t & 63, l15 = lane & 15, l4 = lane >> 4;
    const int wr = w >> 1, wc = w & 1;
    #pragma unroll
    for (int m = 0; m < 4; ++m)
        #pragma unroll
        for (int nb = 0; nb < 4; ++nb) {
            int col = c0 + wc * 64 + nb * 16 + l15;
            int rb  = m0 + wr * 64 + m * 16 + l4 * 4;   // batch base for this lane
            #pragma unroll
            for (int j = 0; j < 4; ++j)
                qkv[((size_t)(rb + j) * 16 + n) * 1280 + col] = __float2bfloat16(acc[m][nb][j]);
        }
}

// ---------------- K4: attention, MFMA + LDS V-transpose, block per b ---------------
__global__ __launch_bounds__(256)
void k4_attn(const hbf* __restrict__ qkv, const float* __restrict__ maskg,
             hbf* __restrict__ ctx)
{
    const int b = blockIdx.x;
    const int t = threadIdx.x;
    const int w = t >> 6, lane = t & 63;
    const int l15 = lane & 15, g = lane >> 4;

    __shared__ hbf vS[16 * 1024];   // V[m][h*256+d], 32KB

    // stage V coalesced: thread (r=t>>4, c=t&15) copies 8x16B of row r
    {
        const int r = t >> 4, c = t & 15;
        const uint4* src = (const uint4*)(qkv + (size_t)(b * 16 + r) * 1280 + 256);
        uint4* dst = (uint4*)(vS + r * 1024);
        #pragma unroll
        for (int i = 0; i < 8; ++i) dst[c + i * 16] = src[c + i * 16];
    }

    // S^T = K @ Q^T : lane holds S[m=4g+j][n=l15]
    const hbf* qrow = qkv + (size_t)(b * 16 + l15) * 1280 + w * 32 + g * 8;
    bf16x8 qf = *(const bf16x8*)(qrow);
    bf16x8 kf = *(const bf16x8*)(qrow + 128);
    f32x4 s = {0.f, 0.f, 0.f, 0.f};
    s = __builtin_amdgcn_mfma_f32_16x16x32_bf16(kf, qf, s, 0, 0, 0);

    const float scale = 0.17677669529663687f;
    float v0 = s[0] * scale, v1 = s[1] * scale, v2 = s[2] * scale, v3 = s[3] * scale;
    float mx = fmaxf(fmaxf(v0, v1), fmaxf(v2, v3));
    mx = fmaxf(mx, __shfl_xor(mx, 16));
    mx = fmaxf(mx, __shfl_xor(mx, 32));
    float e0 = expf(v0 - mx), e1 = expf(v1 - mx), e2 = expf(v2 - mx), e3 = expf(v3 - mx);
    float sm = e0 + e1 + e2 + e3;
    sm += __shfl_xor(sm, 16);
    sm += __shfl_xor(sm, 32);
    float inv = maskg[b * NRIM + l15] / sm;   // row-mask * softmax-normalize

    // P^T regs -> B-fragment for PV mfma (lane n=l15 needs m=8g..8g+7; zero g>=2)
    unsigned u0 = packbf(e0 * inv, e1 * inv);
    unsigned u1 = packbf(e2 * inv, e3 * inv);
    int sl = l15 + (g << 5);
    unsigned f0 = __shfl((int)u0, sl);
    unsigned f1 = __shfl((int)u1, sl);
    unsigned f2 = __shfl((int)u0, sl + 16);
    unsigned f3 = __shfl((int)u1, sl + 16);
    if (lane >= 32) { f0 = 0; f1 = 0; f2 = 0; f3 = 0; }
    union { unsigned u[4]; bf16x8 v; } pf;
    pf.u[0] = f0; pf.u[1] = f1; pf.u[2] = f2; pf.u[3] = f3;

    __syncthreads();

    // PV: A-frag lane (row=l15 -> d_local, g -> m-group) from LDS column reads
    const unsigned short* vsu = (const unsigned short*)vS;
    const int vbase = (8 * (g & 1)) * 1024 + w * 256 + l15;   // + e*1024 + dc*16
    hbf* crow = ctx + (size_t)(b * 16 + l15) * 1024 + w * 256 + g * 4;
    #pragma unroll
    for (int dc = 0; dc < 16; ++dc) {
        union { unsigned short u[8]; bf16x8 v; } vf;
        #pragma unroll
        for (int e = 0; e < 8; ++e)
            vf.u[e] = vsu[vbase + e * 1024 + dc * 16];
        f32x4 o = {0.f, 0.f, 0.f, 0.f};
        o = __builtin_amdgcn_mfma_f32_16x16x32_bf16(vf.v, pf.v, o, 0, 0, 0);
        unsigned lo = packbf(o[0], o[1]);
        unsigned hi = packbf(o[2], o[3]);
        *(uint2*)(crow + dc * 16) = make_uint2(lo, hi);
    }
}

// ---------------- K5 GEMM: out = mask ? ctx @ Wout^T + hy : hs ---------------------
__global__ __launch_bounds__(256)
void k5g(const hbf* __restrict__ ctx, const hbf* __restrict__ Wout,
         const hbf* __restrict__ hyB, const float* __restrict__ hs,
         const float* __restrict__ maskg, float* __restrict__ out)
{
    __shared__ __align__(16) short As[128 * 64];
    __shared__ __align__(16) short Bs[128 * 64];
    const int id = blockIdx.x;
    const int xcd = id & 7, idx = id >> 3;          // idx in [0,64)
    const int n  = xcd + ((idx >> 5) << 3);
    const int rem = idx & 31;
    const int m0 = (rem >> 1) * 128;
    const int c0 = (rem & 1) * 128;

    const hbf* A = ctx + (size_t)n * 1024 + (size_t)m0 * (NRIM * 1024);
    const hbf* B = Wout + (size_t)n * (256 * 1024) + (size_t)c0 * 1024;

    f32x4 acc[4][4];
    f32x4 zz = {0.0f, 0.0f, 0.0f, 0.0f};
    #pragma unroll
    for (int m = 0; m < 4; ++m)
        #pragma unroll
        for (int nb = 0; nb < 4; ++nb) acc[m][nb] = zz;

    gemm_core64(A, NRIM * 1024, B, 1024, 1024, As, Bs, acc);

    const int t = threadIdx.x;
    const int w = t >> 6, lane = t & 63, l15 = lane & 15, l4 = lane >> 4;
    const int wr = w >> 1, wc = w & 1;
    #pragma unroll
    for (int m = 0; m < 4; ++m)
        #pragma unroll
        for (int nb = 0; nb < 4; ++nb) {
            int col = c0 + wc * 64 + nb * 16 + l15;
            #pragma unroll
            for (int j = 0; j < 4; ++j) {
                int row = m0 + wr * 64 + m * 16 + l4 * 4 + j;
                size_t idx2 = ((size_t)row * NRIM + n) * HID + col;
                float mk = maskg[row * NRIM + n];
                out[idx2] = (mk > 0.5f) ? (acc[m][nb][j] + __bfloat162float(hyB[idx2]))
                                        : hs[idx2];
            }
        }
}

extern "C" void kernel_launch(void* const* d_in, const int* in_sizes, int n_in,
                              void* d_out, int out_size, void* d_ws, size_t ws_size,
                              hipStream_t stream) {
    const float* x       = (const float*)d_in[0];
    const float* hs      = (const float*)d_in[1];
    const float* option  = (const float*)d_in[2];
    const float* value_w = (const float*)d_in[3];
    const float* value_b = (const float*)d_in[4];
    const float* p_w     = (const float*)d_in[5];
    const float* p_b     = (const float*)d_in[6];
    const float* x2h_w   = (const float*)d_in[7];
    const float* h2h_w   = (const float*)d_in[8];
    const float* q_w     = (const float*)d_in[9];
    const float* k_w     = (const float*)d_in[10];
    const float* v_w     = (const float*)d_in[11];
    const float* out_w   = (const float*)d_in[12];
    float* out = (float*)d_out;

    char* ws = (char*)d_ws;
    // region0: A2 (46.1 MB) / ctx (67 MB) union  (A2 dead after k2g)
    hbf* A2   = (hbf*)(ws);
    hbf* ctx  = (hbf*)(ws);
    size_t off = 67108864;
    // region1: qkv (84 MB)
    hbf* qkv  = (hbf*)(ws + off);
    off += 83886080;
    hbf* W2   = (hbf*)(ws + off); off += 23068672;   // [16][1024][704]
    hbf* Wqkv = (hbf*)(ws + off); off += 10485760;   // [16][1280][256]
    hbf* Wout = (hbf*)(ws + off); off += 8388608;    // [16][256][1024]
    hbf* hyB  = (hbf*)(ws + off); off += 16777216;   // [32768][256]
    float* vl0   = (float*)(ws + off); off += 4194304;   // [2048][512] f32
    hbf* xB   = (hbf*)(ws + off); off += 2097152;    // [2048][512] bf16
    hbf* Wv   = (hbf*)(ws + off); off += 524288;     // [512][512] bf16
    float* p0g   = (float*)(ws + off); off += 131072;
    float* maskg = (float*)(ws + off); off += 131072;

    // --- all prep (weight transposes, zeros, gating scores, x->bf16) in ONE launch
    mega_prep<<<dim3(20364), dim3(256), 0, stream>>>(
        h2h_w, x2h_w, q_w, k_w, v_w, out_w, value_w, option, p_w, p_b, x,
        W2, Wqkv, Wout, Wv, p0g, maskg, xB);

    // --- value GEMM + input assembly ---
    k1v<<<dim3(64), dim3(256), 0, stream>>>(xB, Wv, value_b, vl0);
    k1b_a2<<<dim3(BATCH), dim3(256), 0, stream>>>(hs, vl0, p0g, maskg, value_b, A2);

    // --- GRU gates GEMM with fused GRU epilogue -> hyB ---
    k2g<<<dim3(2048), dim3(256), 0, stream>>>(A2, W2, hyB);

    // --- QKV GEMM (coalesced single buffer) ---
    k3g<<<dim3(2560), dim3(256), 0, stream>>>(hyB, Wqkv, qkv);

    // --- attention (MFMA + LDS V-transpose) ---
    k4_attn<<<dim3(BATCH), dim3(256), 0, stream>>>(qkv, maskg, ctx);

    // --- output projection GEMM (fused mask/residual) ---
    k5g<<<dim3(512), dim3(256), 0, stream>>>(ctx, Wout, hyB, hs, maskg, out);
}

// Round 9
// 248.985 us; speedup vs baseline: 1.9935x; 1.0443x over previous
//
#include <hip/hip_runtime.h>
#include <hip/hip_bf16.h>
#include <math.h>

#define BATCH 2048
#define INDIM 512
#define HID   256
#define NRIM  16
#define VAL   400
#define ONUM  8
#define CH    4
#define CK    32
#define CV    256
#define KACT  8
#define K2P   704   // GRU K padded to multiple of 64 (672 -> 704)

typedef __hip_bfloat16 hbf;
typedef __attribute__((ext_vector_type(8))) __bf16 bf16x8;
typedef __attribute__((ext_vector_type(4))) float f32x4;

__device__ __forceinline__ float fsig(float x) {
    x = fminf(fmaxf(x, -30.0f), 30.0f);
    return 1.0f / (1.0f + __expf(-x));
}
__device__ __forceinline__ float ftanh_(float x) {
    x = fminf(fmaxf(x, -15.0f), 15.0f);
    float e = __expf(2.0f * x);
    return (e - 1.0f) / (e + 1.0f);
}

__device__ __forceinline__ unsigned packbf(float a, float b) {
    hbf ha = __float2bfloat16(a), hb = __float2bfloat16(b);
    unsigned short ua, ub;
    __builtin_memcpy(&ua, &ha, 2);
    __builtin_memcpy(&ub, &hb, 2);
    return ((unsigned)ub << 16) | ua;
}

#define GLL(g, l) __builtin_amdgcn_global_load_lds(                                   \
    (const __attribute__((address_space(1))) void*)(g),                               \
    (__attribute__((address_space(3))) void*)(l), 16, 0, 0)

// ---------------- transpose+convert body: dst[n][coff+cmap(c)][koff+k] = src[n][k][c]
__device__ __forceinline__ void t_conv_body(
    const float* __restrict__ src, hbf* __restrict__ dst,
    int K, int C, long s_ns, long d_ns, int dstride,
    int koff, int coff, int cmode, int bx, int by, int bz, float* tileS)
{
    const int c0 = bx * 32, k0 = by * 32;
    const int tx = threadIdx.x & 31, ty = threadIdx.x >> 5;
    float (*tile)[33] = (float(*)[33])tileS;
    const float* s = src + (size_t)bz * s_ns;
    #pragma unroll
    for (int i = 0; i < 4; ++i) {
        int k = k0 + ty + i * 8, c = c0 + tx;
        tile[ty + i * 8][tx] = (k < K && c < C) ? s[(size_t)k * C + c] : 0.0f;
    }
    __syncthreads();
    hbf* d = dst + (size_t)bz * d_ns;
    #pragma unroll
    for (int i = 0; i < 4; ++i) {
        int c = c0 + ty + i * 8, k = k0 + tx;
        if (c < C && k < K) {
            int cc = coff + (cmode ? (c < 512 ? c : c + 256) : c);
            d[(size_t)cc * dstride + koff + k] = __float2bfloat16(tile[tx][ty + i * 8]);
        }
    }
}

// ---------------- mega_prep: all weight transposes + targeted zeros + k1s + k_xb ---
__global__ __launch_bounds__(256)
void mega_prep(const float* __restrict__ h2h_w, const float* __restrict__ x2h_w,
               const float* __restrict__ q_w, const float* __restrict__ k_w,
               const float* __restrict__ v_w, const float* __restrict__ out_w,
               const float* __restrict__ value_w, const float* __restrict__ option,
               const float* __restrict__ p_w, const float* __restrict__ p_b,
               const float* __restrict__ x,
               hbf* __restrict__ W2, hbf* __restrict__ Wqkv, hbf* __restrict__ Wout,
               hbf* __restrict__ Wv, float* __restrict__ p0g, float* __restrict__ maskg,
               hbf* __restrict__ xB)
{
    __shared__ float tileS[32 * 33];
    const int id = blockIdx.x;
    const int t  = threadIdx.x;

    if (id < 3072) {
        int l = id, bz = l / 192, rem = l % 192;
        t_conv_body(h2h_w, W2, 256, 768, 196608L, 720896L, K2P, 0, 0, 1,
                    rem % 24, rem / 24, bz, tileS);
    } else if (id < 8064) {
        int l = id - 3072, bz = l / 312, rem = l % 312;
        t_conv_body(x2h_w, W2, 400, 768, 307200L, 720896L, K2P, 256, 0, 0,
                    rem % 24, rem / 24, bz, tileS);
    } else if (id < 8576) {
        int l = id - 8064, bz = l / 32, rem = l % 32;
        t_conv_body(q_w, Wqkv, 256, 128, 32768L, 327680L, 256, 0, 0, 0,
                    rem % 4, rem / 4, bz, tileS);
    } else if (id < 9088) {
        int l = id - 8576, bz = l / 32, rem = l % 32;
        t_conv_body(k_w, Wqkv, 256, 128, 32768L, 327680L, 256, 0, 128, 0,
                    rem % 4, rem / 4, bz, tileS);
    } else if (id < 13184) {
        int l = id - 9088, bz = l / 256, rem = l % 256;
        t_conv_body(v_w, Wqkv, 256, 1024, 262144L, 327680L, 256, 0, 256, 0,
                    rem % 32, rem / 32, bz, tileS);
    } else if (id < 17280) {
        int l = id - 13184, bz = l / 256, rem = l % 256;
        t_conv_body(out_w, Wout, 1024, 256, 262144L, 262144L, 1024, 0, 0, 0,
                    rem % 8, rem / 8, bz, tileS);
    } else if (id < 17488) {
        int l = id - 17280;
        t_conv_body(value_w, Wv, 512, 400, 0L, 0L, 512, 0, 0, 0,
                    l % 13, l / 13, 0, tileS);
    } else if (id < 18672) {
        int l = id - 17488, n = l / 74, idx = (l % 74) * 256 + t;
        uint4 z; z.x = 0; z.y = 0; z.z = 0; z.w = 0;
        uint4* base = (uint4*)(W2 + (size_t)n * 720896);
        if (idx < 14336) {
            int c = 768 + idx / 56, u = 32 + idx % 56;
            base[(size_t)c * 88 + u] = z;
        } else {
            int i2 = idx - 14336;
            int c = i2 / 6, u = 82 + i2 % 6;
            base[(size_t)c * 88 + u] = z;
        }
    } else if (id < 18700) {
        int idx = (id - 18672) * 256 + t;
        int c = 400 + idx / 64, u = idx % 64;
        uint4 z; z.x = 0; z.y = 0; z.z = 0; z.w = 0;
        ((uint4*)Wv)[(size_t)c * 64 + u] = z;
    } else if (id < 19212) {
        int l = id - 18700, n = l / 32, idx = (l % 32) * 256 + t;
        int c = 512 + idx / 32, u = idx % 32;
        uint4 z; z.x = 0; z.y = 0; z.z = 0; z.w = 0;
        ((uint4*)(W2 + (size_t)n * 720896))[(size_t)c * 88 + u] = z;
    } else if (id < 19340) {
        const int bb = t >> 4, n = t & 15;
        const int b  = (id - 19212) * 16 + bb;
        float (*sc)[17] = (float(*)[17])tileS;
        float s0 = p_b[n], s1 = 0.0f;
        #pragma unroll
        for (int o = 0; o < ONUM; ++o) {
            s0 = fmaf(option[(b * 2 + 0) * ONUM + o], p_w[o * NRIM + n], s0);
            s1 = fmaf(option[(b * 2 + 1) * ONUM + o], p_w[o * NRIM + n], s1);
        }
        sc[bb][n] = s0;
        __syncthreads();
        int rank = 0;
        #pragma unroll
        for (int m = 0; m < NRIM; ++m) {
            float sm = sc[bb][m];
            if (sm > s0 || (sm == s0 && m < n)) rank++;
        }
        float mk = (rank < KACT) ? 1.0f : 0.0f;
        float mx = fmaxf(s0, s1);
        float e0 = __expf(s0 - mx), e1 = __expf(s1 - mx);
        p0g[b * NRIM + n]   = e0 / (e0 + e1);
        maskg[b * NRIM + n] = mk;
    } else {
        int i = (id - 19340) * 256 + t;
        float4 v = ((const float4*)x)[i];
        unsigned lo = packbf(v.x, v.y), hi = packbf(v.z, v.w);
        *(uint2*)(xB + (size_t)i * 4) = make_uint2(lo, hi);
    }
}

// ---------------- K1b: A2[b][n][K2P] = [ bf16(hs) | masked inputs | 0 pad ] --------
__global__ __launch_bounds__(256)
void k1b_a2(const float* __restrict__ hs, const float* __restrict__ vl0,
            const float* __restrict__ p0g, const float* __restrict__ maskg,
            const float* __restrict__ value_b, hbf* __restrict__ A2)
{
    const int b = blockIdx.x;
    const int t = threadIdx.x;
    __shared__ float vS[VAL], bS[VAL];
    if (t < 100) {
        ((float4*)vS)[t] = ((const float4*)(vl0 + (size_t)b * 512))[t];
        ((float4*)bS)[t] = ((const float4*)value_b)[t];
    }
    __syncthreads();

    for (int n = 0; n < NRIM; ++n) {
        size_t ro = ((size_t)b * NRIM + n) * K2P;
        float p0 = p0g[b * NRIM + n], mk = maskg[b * NRIM + n];
        if (t < 128) {
            float2 hv = ((const float2*)(hs + ((size_t)b * NRIM + n) * HID))[t];
            ((unsigned*)(A2 + ro))[t] = packbf(hv.x, hv.y);
        } else if (t < 152) {
            ((unsigned*)(A2 + ro + 656))[t - 128] = 0;
        }
        if (t < 200) {
            float a0 = mk * (p0 * vS[2 * t]     + (1.0f - p0) * bS[2 * t]);
            float a1 = mk * (p0 * vS[2 * t + 1] + (1.0f - p0) * bS[2 * t + 1]);
            ((unsigned*)(A2 + ro + 256))[t] = packbf(a0, a1);
        }
    }
}

// ------ MFMA GEMM core: BK=64, swizzled LDS, loop-carried pointers -----------------
__device__ __forceinline__ void gemm_core64(const hbf* __restrict__ A, long lda,
                                            const hbf* __restrict__ B, long ldb,
                                            int K, short* As, short* Bs, f32x4 acc[4][4])
{
    const int t = threadIdx.x;
    const int w = t >> 6, lane = t & 63;
    const int l15 = lane & 15, l4 = lane >> 4;
    const int rl = lane >> 3;
    const int gu = (lane & 7) ^ rl;
    const int l7 = l15 & 7;

    const hbf* pa[4];
    const hbf* pb[4];
    #pragma unroll
    for (int q = 0; q < 4; ++q) {
        int row = q * 32 + w * 8 + rl;
        pa[q] = A + (size_t)row * lda + gu * 8;
        pb[q] = B + (size_t)row * ldb + gu * 8;
    }

    for (int kk = 0; kk < K; kk += 64) {
        __syncthreads();
        #pragma unroll
        for (int q = 0; q < 4; ++q) {
            GLL(pa[q], As + (q * 32 + w * 8) * 64);
            GLL(pb[q], Bs + (q * 32 + w * 8) * 64);
            pa[q] += 64; pb[q] += 64;
        }
        __syncthreads();

        const int wr = w >> 1, wc = w & 1;
        #pragma unroll
        for (int ks = 0; ks < 2; ++ks) {
            const int p = (ks * 4 + l4) ^ l7;
            bf16x8 af[4], bfr[4];
            #pragma unroll
            for (int m = 0; m < 4; ++m)
                af[m] = *(const bf16x8*)(As + (wr * 64 + m * 16 + l15) * 64 + p * 8);
            #pragma unroll
            for (int nb = 0; nb < 4; ++nb)
                bfr[nb] = *(const bf16x8*)(Bs + (wc * 64 + nb * 16 + l15) * 64 + p * 8);
            #pragma unroll
            for (int m = 0; m < 4; ++m)
                #pragma unroll
                for (int nb = 0; nb < 4; ++nb)
                    acc[m][nb] = __builtin_amdgcn_mfma_f32_16x16x32_bf16(af[m], bfr[nb], acc[m][nb], 0, 0, 0);
        }
    }
}

// ---------------- K1v GEMM: vl0[2048][512] = xB @ Wv^T + value_b -------------------
__global__ __launch_bounds__(256)
void k1v(const hbf* __restrict__ xB, const hbf* __restrict__ Wv,
         const float* __restrict__ value_b, float* __restrict__ vl0)
{
    __shared__ __align__(16) short As[128 * 64];
    __shared__ __align__(16) short Bs[128 * 64];
    const int m0 = (blockIdx.x >> 2) * 128;
    const int c0 = (blockIdx.x & 3) * 128;

    const hbf* A = xB + (size_t)m0 * INDIM;
    const hbf* B = Wv + (size_t)c0 * INDIM;

    f32x4 acc[4][4];
    f32x4 zz = {0.0f, 0.0f, 0.0f, 0.0f};
    #pragma unroll
    for (int m = 0; m < 4; ++m)
        #pragma unroll
        for (int nb = 0; nb < 4; ++nb) acc[m][nb] = zz;

    gemm_core64(A, INDIM, B, INDIM, INDIM, As, Bs, acc);

    const int t = threadIdx.x;
    const int w = t >> 6, lane = t & 63, l15 = lane & 15, l4 = lane >> 4;
    const int wr = w >> 1, wc = w & 1;
    #pragma unroll
    for (int nb = 0; nb < 4; ++nb) {
        int col = c0 + wc * 64 + nb * 16 + l15;
        float bias = (col < VAL) ? value_b[col] : 0.0f;
        #pragma unroll
        for (int m = 0; m < 4; ++m)
            #pragma unroll
            for (int j = 0; j < 4; ++j) {
                int row = m0 + wr * 64 + m * 16 + l4 * 4 + j;
                vl0[(size_t)row * 512 + col] = acc[m][nb][j] + bias;
            }
    }
}

// ------ K2 GEMM + fused GRU: B-cols = 4 gates x 32 hidden cols; writes hyB directly
__global__ __launch_bounds__(256)
void k2g(const hbf* __restrict__ A2, const hbf* __restrict__ W2, hbf* __restrict__ hyB)
{
    __shared__ __align__(16) short As[128 * 64];
    __shared__ __align__(16) short Bs[128 * 64];
    const int id = blockIdx.x;
    const int xcd = id & 7, idx = id >> 3;
    const int n  = xcd + ((idx >> 7) << 3);
    const int rem = idx & 127;
    const int m0 = (rem >> 3) * 128;       // batch-tile base
    const int c0 = rem & 7;                // hidden-col strip [0,8)

    const hbf* A = A2 + (size_t)n * K2P + (size_t)m0 * (NRIM * K2P);
    const hbf* Bb = W2 + (size_t)n * (1024 * K2P);

    const int t = threadIdx.x;
    const int w = t >> 6, lane = t & 63;
    const int l15 = lane & 15, l4 = lane >> 4;
    const int rl = lane >> 3;
    const int gu = (lane & 7) ^ rl;
    const int l7 = l15 & 7;
    const int wr = w >> 1, wc = w & 1;

    f32x4 acc[4][4];
    f32x4 zz = {0.0f, 0.0f, 0.0f, 0.0f};
    #pragma unroll
    for (int m = 0; m < 4; ++m)
        #pragma unroll
        for (int nb = 0; nb < 4; ++nb) acc[m][nb] = zz;

    // loop-carried pointers (gate remap hoisted out of the K-loop)
    const hbf* pa[4];
    const hbf* pb[4];
    #pragma unroll
    for (int q = 0; q < 4; ++q) {
        int row = q * 32 + w * 8 + rl;
        int wrow = ((row >> 4) & 3) * 256 + c0 * 32 + ((row >> 6) << 4) + (row & 15);
        pa[q] = A + (size_t)row * (NRIM * K2P) + gu * 8;
        pb[q] = Bb + (size_t)wrow * K2P + gu * 8;
    }

    for (int kk = 0; kk < K2P; kk += 64) {
        __syncthreads();
        #pragma unroll
        for (int q = 0; q < 4; ++q) {
            GLL(pa[q], As + (q * 32 + w * 8) * 64);
            GLL(pb[q], Bs + (q * 32 + w * 8) * 64);
            pa[q] += 64; pb[q] += 64;
        }
        __syncthreads();

        #pragma unroll
        for (int ks = 0; ks < 2; ++ks) {
            const int p = (ks * 4 + l4) ^ l7;
            bf16x8 af[4], bfr[4];
            #pragma unroll
            for (int m = 0; m < 4; ++m)
                af[m] = *(const bf16x8*)(As + (wr * 64 + m * 16 + l15) * 64 + p * 8);
            #pragma unroll
            for (int nb = 0; nb < 4; ++nb)
                bfr[nb] = *(const bf16x8*)(Bs + (wc * 64 + nb * 16 + l15) * 64 + p * 8);
            #pragma unroll
            for (int m = 0; m < 4; ++m)
                #pragma unroll
                for (int nb = 0; nb < 4; ++nb)
                    acc[m][nb] = __builtin_amdgcn_mfma_f32_16x16x32_bf16(af[m], bfr[nb], acc[m][nb], 0, 0, 0);
        }
    }

    // fused GRU epilogue: acc[m][gate][j]; col = c0*32 + wc*16 + l15
    const int col = c0 * 32 + wc * 16 + l15;
    #pragma unroll
    for (int m = 0; m < 4; ++m)
        #pragma unroll
        for (int j = 0; j < 4; ++j) {
            int row = m0 + wr * 64 + m * 16 + l4 * 4 + j;     // batch index
            size_t ridx = (size_t)row * NRIM + n;
            float reset = fsig(acc[m][0][j]);
            float inp   = fsig(acc[m][1][j]);
            float newg  = ftanh_(acc[m][2][j] + reset * acc[m][3][j]);
            float h     = __bfloat162float(A2[ridx * K2P + col]);
            hyB[ridx * HID + col] = __float2bfloat16(newg + inp * (h - newg));
        }
}

// ---------------- K3 GEMM: qkv[(b*16+n)][1280] = hy @ Wqkv^T (coalesced) -----------
__global__ __launch_bounds__(256)
void k3g(const hbf* __restrict__ hyB, const hbf* __restrict__ Wqkv, hbf* __restrict__ qkv)
{
    __shared__ __align__(16) short As[128 * 64];
    __shared__ __align__(16) short Bs[128 * 64];
    const int id = blockIdx.x;
    const int xcd = id & 7, idx = id >> 3;          // idx in [0,320)
    const int n  = xcd + (idx / 160) * 8;
    const int rem = idx % 160;
    const int m0 = (rem / 10) * 128;                // batch-tile base
    const int c0 = (rem % 10) * 128;

    const hbf* A = hyB + (size_t)n * HID + (size_t)m0 * (NRIM * HID);
    const hbf* B = Wqkv + (size_t)n * (1280 * 256) + (size_t)c0 * 256;

    f32x4 acc[4][4];
    f32x4 zz = {0.0f, 0.0f, 0.0f, 0.0f};
    #pragma unroll
    for (int m = 0; m < 4; ++m)
        #pragma unroll
        for (int nb = 0; nb < 4; ++nb) acc[m][nb] = zz;

    gemm_core64(A, NRIM * HID, B, 256, 256, As, Bs, acc);

    const int t = threadIdx.x;
    const int w = t >> 6, lane = t & 63, l15 = lane & 15, l4 = lane >> 4;
    const int wr = w >> 1, wc = w & 1;
    #pragma unroll
    for (int m = 0; m < 4; ++m)
        #pragma unroll
        for (int nb = 0; nb < 4; ++nb) {
            int col = c0 + wc * 64 + nb * 16 + l15;
            int rb  = m0 + wr * 64 + m * 16 + l4 * 4;   // batch base for this lane
            #pragma unroll
            for (int j = 0; j < 4; ++j)
                qkv[((size_t)(rb + j) * 16 + n) * 1280 + col] = __float2bfloat16(acc[m][nb][j]);
        }
}

// ---------------- K4: attention, MFMA + LDS V-transpose, block per b ---------------
__global__ __launch_bounds__(256)
void k4_attn(const hbf* __restrict__ qkv, const float* __restrict__ maskg,
             hbf* __restrict__ ctx)
{
    const int b = blockIdx.x;
    const int t = threadIdx.x;
    const int w = t >> 6, lane = t & 63;
    const int l15 = lane & 15, g = lane >> 4;

    __shared__ hbf vS[16 * 1024];   // V[m][h*256+d], 32KB

    // stage V coalesced: thread (r=t>>4, c=t&15) copies 8x16B of row r
    {
        const int r = t >> 4, c = t & 15;
        const uint4* src = (const uint4*)(qkv + (size_t)(b * 16 + r) * 1280 + 256);
        uint4* dst = (uint4*)(vS + r * 1024);
        #pragma unroll
        for (int i = 0; i < 8; ++i) dst[c + i * 16] = src[c + i * 16];
    }

    // S^T = K @ Q^T : lane holds S[m=4g+j][n=l15]
    const hbf* qrow = qkv + (size_t)(b * 16 + l15) * 1280 + w * 32 + g * 8;
    bf16x8 qf = *(const bf16x8*)(qrow);
    bf16x8 kf = *(const bf16x8*)(qrow + 128);
    f32x4 s = {0.f, 0.f, 0.f, 0.f};
    s = __builtin_amdgcn_mfma_f32_16x16x32_bf16(kf, qf, s, 0, 0, 0);

    const float scale = 0.17677669529663687f;
    float v0 = s[0] * scale, v1 = s[1] * scale, v2 = s[2] * scale, v3 = s[3] * scale;
    float mx = fmaxf(fmaxf(v0, v1), fmaxf(v2, v3));
    mx = fmaxf(mx, __shfl_xor(mx, 16));
    mx = fmaxf(mx, __shfl_xor(mx, 32));
    float e0 = __expf(v0 - mx), e1 = __expf(v1 - mx);
    float e2 = __expf(v2 - mx), e3 = __expf(v3 - mx);
    float sm = e0 + e1 + e2 + e3;
    sm += __shfl_xor(sm, 16);
    sm += __shfl_xor(sm, 32);
    float inv = maskg[b * NRIM + l15] / sm;   // row-mask * softmax-normalize

    // P^T regs -> B-fragment for PV mfma (lane n=l15 needs m=8g..8g+7; zero g>=2)
    unsigned u0 = packbf(e0 * inv, e1 * inv);
    unsigned u1 = packbf(e2 * inv, e3 * inv);
    int sl = l15 + (g << 5);
    unsigned f0 = __shfl((int)u0, sl);
    unsigned f1 = __shfl((int)u1, sl);
    unsigned f2 = __shfl((int)u0, sl + 16);
    unsigned f3 = __shfl((int)u1, sl + 16);
    if (lane >= 32) { f0 = 0; f1 = 0; f2 = 0; f3 = 0; }
    union { unsigned u[4]; bf16x8 v; } pf;
    pf.u[0] = f0; pf.u[1] = f1; pf.u[2] = f2; pf.u[3] = f3;

    __syncthreads();

    // PV: A-frag lane (row=l15 -> d_local, g -> m-group) from LDS column reads
    const unsigned short* vsu = (const unsigned short*)vS;
    const int vbase = (8 * (g & 1)) * 1024 + w * 256 + l15;   // + e*1024 + dc*16
    hbf* crow = ctx + (size_t)(b * 16 + l15) * 1024 + w * 256 + g * 4;
    #pragma unroll
    for (int dc = 0; dc < 16; ++dc) {
        union { unsigned short u[8]; bf16x8 v; } vf;
        #pragma unroll
        for (int e = 0; e < 8; ++e)
            vf.u[e] = vsu[vbase + e * 1024 + dc * 16];
        f32x4 o = {0.f, 0.f, 0.f, 0.f};
        o = __builtin_amdgcn_mfma_f32_16x16x32_bf16(vf.v, pf.v, o, 0, 0, 0);
        unsigned lo = packbf(o[0], o[1]);
        unsigned hi = packbf(o[2], o[3]);
        *(uint2*)(crow + dc * 16) = make_uint2(lo, hi);
    }
}

// ---------------- K5 GEMM: out = mask ? ctx @ Wout^T + hy : hs ---------------------
__global__ __launch_bounds__(256)
void k5g(const hbf* __restrict__ ctx, const hbf* __restrict__ Wout,
         const hbf* __restrict__ hyB, const float* __restrict__ hs,
         const float* __restrict__ maskg, float* __restrict__ out)
{
    __shared__ __align__(16) short As[128 * 64];
    __shared__ __align__(16) short Bs[128 * 64];
    const int id = blockIdx.x;
    const int xcd = id & 7, idx = id >> 3;          // idx in [0,64)
    const int n  = xcd + ((idx >> 5) << 3);
    const int rem = idx & 31;
    const int m0 = (rem >> 1) * 128;
    const int c0 = (rem & 1) * 128;

    const hbf* A = ctx + (size_t)n * 1024 + (size_t)m0 * (NRIM * 1024);
    const hbf* B = Wout + (size_t)n * (256 * 1024) + (size_t)c0 * 1024;

    f32x4 acc[4][4];
    f32x4 zz = {0.0f, 0.0f, 0.0f, 0.0f};
    #pragma unroll
    for (int m = 0; m < 4; ++m)
        #pragma unroll
        for (int nb = 0; nb < 4; ++nb) acc[m][nb] = zz;

    gemm_core64(A, NRIM * 1024, B, 1024, 1024, As, Bs, acc);

    const int t = threadIdx.x;
    const int w = t >> 6, lane = t & 63, l15 = lane & 15, l4 = lane >> 4;
    const int wr = w >> 1, wc = w & 1;
    #pragma unroll
    for (int m = 0; m < 4; ++m)
        #pragma unroll
        for (int nb = 0; nb < 4; ++nb) {
            int col = c0 + wc * 64 + nb * 16 + l15;
            #pragma unroll
            for (int j = 0; j < 4; ++j) {
                int row = m0 + wr * 64 + m * 16 + l4 * 4 + j;
                size_t idx2 = ((size_t)row * NRIM + n) * HID + col;
                float mk = maskg[row * NRIM + n];
                out[idx2] = (mk > 0.5f) ? (acc[m][nb][j] + __bfloat162float(hyB[idx2]))
                                        : hs[idx2];
            }
        }
}

extern "C" void kernel_launch(void* const* d_in, const int* in_sizes, int n_in,
                              void* d_out, int out_size, void* d_ws, size_t ws_size,
                              hipStream_t stream) {
    const float* x       = (const float*)d_in[0];
    const float* hs      = (const float*)d_in[1];
    const float* option  = (const float*)d_in[2];
    const float* value_w = (const float*)d_in[3];
    const float* value_b = (const float*)d_in[4];
    const float* p_w     = (const float*)d_in[5];
    const float* p_b     = (const float*)d_in[6];
    const float* x2h_w   = (const float*)d_in[7];
    const float* h2h_w   = (const float*)d_in[8];
    const float* q_w     = (const float*)d_in[9];
    const float* k_w     = (const float*)d_in[10];
    const float* v_w     = (const float*)d_in[11];
    const float* out_w   = (const float*)d_in[12];
    float* out = (float*)d_out;

    char* ws = (char*)d_ws;
    hbf* A2   = (hbf*)(ws);
    hbf* ctx  = (hbf*)(ws);
    size_t off = 67108864;
    hbf* qkv  = (hbf*)(ws + off);
    off += 83886080;
    hbf* W2   = (hbf*)(ws + off); off += 23068672;   // [16][1024][704]
    hbf* Wqkv = (hbf*)(ws + off); off += 10485760;   // [16][1280][256]
    hbf* Wout = (hbf*)(ws + off); off += 8388608;    // [16][256][1024]
    hbf* hyB  = (hbf*)(ws + off); off += 16777216;   // [32768][256]
    float* vl0   = (float*)(ws + off); off += 4194304;   // [2048][512] f32
    hbf* xB   = (hbf*)(ws + off); off += 2097152;    // [2048][512] bf16
    hbf* Wv   = (hbf*)(ws + off); off += 524288;     // [512][512] bf16
    float* p0g   = (float*)(ws + off); off += 131072;
    float* maskg = (float*)(ws + off); off += 131072;

    mega_prep<<<dim3(20364), dim3(256), 0, stream>>>(
        h2h_w, x2h_w, q_w, k_w, v_w, out_w, value_w, option, p_w, p_b, x,
        W2, Wqkv, Wout, Wv, p0g, maskg, xB);

    k1v<<<dim3(64), dim3(256), 0, stream>>>(xB, Wv, value_b, vl0);
    k1b_a2<<<dim3(BATCH), dim3(256), 0, stream>>>(hs, vl0, p0g, maskg, value_b, A2);

    k2g<<<dim3(2048), dim3(256), 0, stream>>>(A2, W2, hyB);

    k3g<<<dim3(2560), dim3(256), 0, stream>>>(hyB, Wqkv, qkv);

    k4_attn<<<dim3(BATCH), dim3(256), 0, stream>>>(qkv, maskg, ctx);

    k5g<<<dim3(512), dim3(256), 0, stream>>>(ctx, Wout, hyB, hs, maskg, out);
}

// Round 10
// 229.913 us; speedup vs baseline: 2.1588x; 1.0830x over previous
//
#include <hip/hip_runtime.h>
#include <hip/hip_bf16.h>
#include <math.h>

#define BATCH 2048
#define INDIM 512
#define HID   256
#define NRIM  16
#define VAL   400
#define ONUM  8
#define CH    4
#define CK    32
#define CV    256
#define KACT  8
#define K2P   704   // GRU K padded to multiple of 64 (672 -> 704)

typedef __hip_bfloat16 hbf;
typedef __attribute__((ext_vector_type(8))) __bf16 bf16x8;
typedef __attribute__((ext_vector_type(4))) float f32x4;

__device__ __forceinline__ float fsig(float x) {
    x = fminf(fmaxf(x, -30.0f), 30.0f);
    return 1.0f / (1.0f + __expf(-x));
}
__device__ __forceinline__ float ftanh_(float x) {
    x = fminf(fmaxf(x, -15.0f), 15.0f);
    float e = __expf(2.0f * x);
    return (e - 1.0f) / (e + 1.0f);
}

__device__ __forceinline__ unsigned packbf(float a, float b) {
    hbf ha = __float2bfloat16(a), hb = __float2bfloat16(b);
    unsigned short ua, ub;
    __builtin_memcpy(&ua, &ha, 2);
    __builtin_memcpy(&ub, &hb, 2);
    return ((unsigned)ub << 16) | ua;
}

#define GLL(g, l) __builtin_amdgcn_global_load_lds(                                   \
    (const __attribute__((address_space(1))) void*)(g),                               \
    (__attribute__((address_space(3))) void*)(l), 16, 0, 0)

// ---------------- transpose+convert body: dst[n][coff+cmap(c)][koff+k] = src[n][k][c]
__device__ __forceinline__ void t_conv_body(
    const float* __restrict__ src, hbf* __restrict__ dst,
    int K, int C, long s_ns, long d_ns, int dstride,
    int koff, int coff, int cmode, int bx, int by, int bz, float* tileS)
{
    const int c0 = bx * 32, k0 = by * 32;
    const int tx = threadIdx.x & 31, ty = threadIdx.x >> 5;
    float (*tile)[33] = (float(*)[33])tileS;
    const float* s = src + (size_t)bz * s_ns;
    #pragma unroll
    for (int i = 0; i < 4; ++i) {
        int k = k0 + ty + i * 8, c = c0 + tx;
        tile[ty + i * 8][tx] = (k < K && c < C) ? s[(size_t)k * C + c] : 0.0f;
    }
    __syncthreads();
    hbf* d = dst + (size_t)bz * d_ns;
    #pragma unroll
    for (int i = 0; i < 4; ++i) {
        int c = c0 + ty + i * 8, k = k0 + tx;
        if (c < C && k < K) {
            int cc = coff + (cmode ? (c < 512 ? c : c + 256) : c);
            d[(size_t)cc * dstride + koff + k] = __float2bfloat16(tile[tx][ty + i * 8]);
        }
    }
}

// ---------------- mega_prep: all weight transposes + targeted zeros + k1s + k_xb ---
__global__ __launch_bounds__(256)
void mega_prep(const float* __restrict__ h2h_w, const float* __restrict__ x2h_w,
               const float* __restrict__ q_w, const float* __restrict__ k_w,
               const float* __restrict__ v_w, const float* __restrict__ out_w,
               const float* __restrict__ value_w, const float* __restrict__ option,
               const float* __restrict__ p_w, const float* __restrict__ p_b,
               const float* __restrict__ x,
               hbf* __restrict__ W2, hbf* __restrict__ Wqkv, hbf* __restrict__ Wout,
               hbf* __restrict__ Wv, float* __restrict__ p0g, float* __restrict__ maskg,
               hbf* __restrict__ xB)
{
    __shared__ float tileS[32 * 33];
    const int id = blockIdx.x;
    const int t  = threadIdx.x;

    if (id < 3072) {
        int l = id, bz = l / 192, rem = l % 192;
        t_conv_body(h2h_w, W2, 256, 768, 196608L, 720896L, K2P, 0, 0, 1,
                    rem % 24, rem / 24, bz, tileS);
    } else if (id < 8064) {
        int l = id - 3072, bz = l / 312, rem = l % 312;
        t_conv_body(x2h_w, W2, 400, 768, 307200L, 720896L, K2P, 256, 0, 0,
                    rem % 24, rem / 24, bz, tileS);
    } else if (id < 8576) {
        int l = id - 8064, bz = l / 32, rem = l % 32;
        t_conv_body(q_w, Wqkv, 256, 128, 32768L, 327680L, 256, 0, 0, 0,
                    rem % 4, rem / 4, bz, tileS);
    } else if (id < 9088) {
        int l = id - 8576, bz = l / 32, rem = l % 32;
        t_conv_body(k_w, Wqkv, 256, 128, 32768L, 327680L, 256, 0, 128, 0,
                    rem % 4, rem / 4, bz, tileS);
    } else if (id < 13184) {
        int l = id - 9088, bz = l / 256, rem = l % 256;
        t_conv_body(v_w, Wqkv, 256, 1024, 262144L, 327680L, 256, 0, 256, 0,
                    rem % 32, rem / 32, bz, tileS);
    } else if (id < 17280) {
        int l = id - 13184, bz = l / 256, rem = l % 256;
        t_conv_body(out_w, Wout, 1024, 256, 262144L, 262144L, 1024, 0, 0, 0,
                    rem % 8, rem / 8, bz, tileS);
    } else if (id < 17488) {
        int l = id - 17280;
        t_conv_body(value_w, Wv, 512, 400, 0L, 0L, 512, 0, 0, 0,
                    l % 13, l / 13, 0, tileS);
    } else if (id < 18672) {
        int l = id - 17488, n = l / 74, idx = (l % 74) * 256 + t;
        uint4 z; z.x = 0; z.y = 0; z.z = 0; z.w = 0;
        uint4* base = (uint4*)(W2 + (size_t)n * 720896);
        if (idx < 14336) {
            int c = 768 + idx / 56, u = 32 + idx % 56;
            base[(size_t)c * 88 + u] = z;
        } else {
            int i2 = idx - 14336;
            int c = i2 / 6, u = 82 + i2 % 6;
            base[(size_t)c * 88 + u] = z;
        }
    } else if (id < 18700) {
        int idx = (id - 18672) * 256 + t;
        int c = 400 + idx / 64, u = idx % 64;
        uint4 z; z.x = 0; z.y = 0; z.z = 0; z.w = 0;
        ((uint4*)Wv)[(size_t)c * 64 + u] = z;
    } else if (id < 19212) {
        int l = id - 18700, n = l / 32, idx = (l % 32) * 256 + t;
        int c = 512 + idx / 32, u = idx % 32;
        uint4 z; z.x = 0; z.y = 0; z.z = 0; z.w = 0;
        ((uint4*)(W2 + (size_t)n * 720896))[(size_t)c * 88 + u] = z;
    } else if (id < 19340) {
        const int bb = t >> 4, n = t & 15;
        const int b  = (id - 19212) * 16 + bb;
        float (*sc)[17] = (float(*)[17])tileS;
        float s0 = p_b[n], s1 = 0.0f;
        #pragma unroll
        for (int o = 0; o < ONUM; ++o) {
            s0 = fmaf(option[(b * 2 + 0) * ONUM + o], p_w[o * NRIM + n], s0);
            s1 = fmaf(option[(b * 2 + 1) * ONUM + o], p_w[o * NRIM + n], s1);
        }
        sc[bb][n] = s0;
        __syncthreads();
        int rank = 0;
        #pragma unroll
        for (int m = 0; m < NRIM; ++m) {
            float sm = sc[bb][m];
            if (sm > s0 || (sm == s0 && m < n)) rank++;
        }
        float mk = (rank < KACT) ? 1.0f : 0.0f;
        float mx = fmaxf(s0, s1);
        float e0 = __expf(s0 - mx), e1 = __expf(s1 - mx);
        p0g[b * NRIM + n]   = e0 / (e0 + e1);
        maskg[b * NRIM + n] = mk;
    } else {
        int i = (id - 19340) * 256 + t;
        float4 v = ((const float4*)x)[i];
        unsigned lo = packbf(v.x, v.y), hi = packbf(v.z, v.w);
        *(uint2*)(xB + (size_t)i * 4) = make_uint2(lo, hi);
    }
}

// ---------------- K1b: A2[b][n][K2P] = [ bf16(hs) | masked inputs | 0 pad ] --------
__global__ __launch_bounds__(256)
void k1b_a2(const float* __restrict__ hs, const float* __restrict__ vl0,
            const float* __restrict__ p0g, const float* __restrict__ maskg,
            const float* __restrict__ value_b, hbf* __restrict__ A2)
{
    const int b = blockIdx.x;
    const int t = threadIdx.x;
    __shared__ float vS[VAL], bS[VAL];
    if (t < 100) {
        ((float4*)vS)[t] = ((const float4*)(vl0 + (size_t)b * 512))[t];
        ((float4*)bS)[t] = ((const float4*)value_b)[t];
    }
    __syncthreads();

    for (int n = 0; n < NRIM; ++n) {
        size_t ro = ((size_t)b * NRIM + n) * K2P;
        float p0 = p0g[b * NRIM + n], mk = maskg[b * NRIM + n];
        if (t < 128) {
            float2 hv = ((const float2*)(hs + ((size_t)b * NRIM + n) * HID))[t];
            ((unsigned*)(A2 + ro))[t] = packbf(hv.x, hv.y);
        } else if (t < 152) {
            ((unsigned*)(A2 + ro + 656))[t - 128] = 0;
        }
        if (t < 200) {
            float a0 = mk * (p0 * vS[2 * t]     + (1.0f - p0) * bS[2 * t]);
            float a1 = mk * (p0 * vS[2 * t + 1] + (1.0f - p0) * bS[2 * t + 1]);
            ((unsigned*)(A2 + ro + 256))[t] = packbf(a0, a1);
        }
    }
}

// ------ MFMA GEMM core: BK=64, swizzled LDS, loop-carried pointers -----------------
__device__ __forceinline__ void gemm_core64(const hbf* __restrict__ A, long lda,
                                            const hbf* __restrict__ B, long ldb,
                                            int K, short* As, short* Bs, f32x4 acc[4][4])
{
    const int t = threadIdx.x;
    const int w = t >> 6, lane = t & 63;
    const int l15 = lane & 15, l4 = lane >> 4;
    const int rl = lane >> 3;
    const int gu = (lane & 7) ^ rl;
    const int l7 = l15 & 7;

    const hbf* pa[4];
    const hbf* pb[4];
    #pragma unroll
    for (int q = 0; q < 4; ++q) {
        int row = q * 32 + w * 8 + rl;
        pa[q] = A + (size_t)row * lda + gu * 8;
        pb[q] = B + (size_t)row * ldb + gu * 8;
    }

    for (int kk = 0; kk < K; kk += 64) {
        __syncthreads();
        #pragma unroll
        for (int q = 0; q < 4; ++q) {
            GLL(pa[q], As + (q * 32 + w * 8) * 64);
            GLL(pb[q], Bs + (q * 32 + w * 8) * 64);
            pa[q] += 64; pb[q] += 64;
        }
        __syncthreads();

        const int wr = w >> 1, wc = w & 1;
        #pragma unroll
        for (int ks = 0; ks < 2; ++ks) {
            const int p = (ks * 4 + l4) ^ l7;
            bf16x8 af[4], bfr[4];
            #pragma unroll
            for (int m = 0; m < 4; ++m)
                af[m] = *(const bf16x8*)(As + (wr * 64 + m * 16 + l15) * 64 + p * 8);
            #pragma unroll
            for (int nb = 0; nb < 4; ++nb)
                bfr[nb] = *(const bf16x8*)(Bs + (wc * 64 + nb * 16 + l15) * 64 + p * 8);
            #pragma unroll
            for (int m = 0; m < 4; ++m)
                #pragma unroll
                for (int nb = 0; nb < 4; ++nb)
                    acc[m][nb] = __builtin_amdgcn_mfma_f32_16x16x32_bf16(af[m], bfr[nb], acc[m][nb], 0, 0, 0);
        }
    }
}

// ---------------- K1v GEMM: vl0[2048][512] = xB @ Wv^T + value_b -------------------
__global__ __launch_bounds__(256)
void k1v(const hbf* __restrict__ xB, const hbf* __restrict__ Wv,
         const float* __restrict__ value_b, float* __restrict__ vl0)
{
    __shared__ __align__(16) short As[128 * 64];
    __shared__ __align__(16) short Bs[128 * 64];
    const int m0 = (blockIdx.x >> 2) * 128;
    const int c0 = (blockIdx.x & 3) * 128;

    const hbf* A = xB + (size_t)m0 * INDIM;
    const hbf* B = Wv + (size_t)c0 * INDIM;

    f32x4 acc[4][4];
    f32x4 zz = {0.0f, 0.0f, 0.0f, 0.0f};
    #pragma unroll
    for (int m = 0; m < 4; ++m)
        #pragma unroll
        for (int nb = 0; nb < 4; ++nb) acc[m][nb] = zz;

    gemm_core64(A, INDIM, B, INDIM, INDIM, As, Bs, acc);

    const int t = threadIdx.x;
    const int w = t >> 6, lane = t & 63, l15 = lane & 15, l4 = lane >> 4;
    const int wr = w >> 1, wc = w & 1;
    #pragma unroll
    for (int nb = 0; nb < 4; ++nb) {
        int col = c0 + wc * 64 + nb * 16 + l15;
        float bias = (col < VAL) ? value_b[col] : 0.0f;
        #pragma unroll
        for (int m = 0; m < 4; ++m)
            #pragma unroll
            for (int j = 0; j < 4; ++j) {
                int row = m0 + wr * 64 + m * 16 + l4 * 4 + j;
                vl0[(size_t)row * 512 + col] = acc[m][nb][j] + bias;
            }
    }
}

// ------ K2 GEMM + fused GRU, gate-aware K-range skipping ---------------------------
// B-cols = 4 gates x 32 hidden cols. Gate of fragment nb == nb; gate of staging
// group (q,w) == (2q + (w>>1)) & 3. Phase 1: K[0,256) = h2h -> gates {0,1,3};
// phase 2: K[256,704) = x2h(+pad) -> gates {0,1,2}. Skipped products are exact 0.
__global__ __launch_bounds__(256)
void k2g(const hbf* __restrict__ A2, const hbf* __restrict__ W2, hbf* __restrict__ hyB)
{
    __shared__ __align__(16) short As[128 * 64];
    __shared__ __align__(16) short Bs[128 * 64];
    const int id = blockIdx.x;
    const int xcd = id & 7, idx = id >> 3;
    const int n  = xcd + ((idx >> 7) << 3);
    const int rem = idx & 127;
    const int m0 = (rem >> 3) * 128;       // batch-tile base
    const int c0 = rem & 7;                // hidden-col strip [0,8)

    const hbf* A = A2 + (size_t)n * K2P + (size_t)m0 * (NRIM * K2P);
    const hbf* Bb = W2 + (size_t)n * (1024 * K2P);

    const int t = threadIdx.x;
    const int w = t >> 6, lane = t & 63;
    const int l15 = lane & 15, l4 = lane >> 4;
    const int rl = lane >> 3;
    const int gu = (lane & 7) ^ rl;
    const int l7 = l15 & 7;
    const int wr = w >> 1, wc = w & 1;

    f32x4 acc[4][4];
    f32x4 zz = {0.0f, 0.0f, 0.0f, 0.0f};
    #pragma unroll
    for (int m = 0; m < 4; ++m)
        #pragma unroll
        for (int nb = 0; nb < 4; ++nb) acc[m][nb] = zz;

    const hbf* pa[4];
    const hbf* pb[4];
    int gq[4];
    #pragma unroll
    for (int q = 0; q < 4; ++q) {
        int row = q * 32 + w * 8 + rl;
        int wrow = ((row >> 4) & 3) * 256 + c0 * 32 + ((row >> 6) << 4) + (row & 15);
        pa[q] = A + (size_t)row * (NRIM * K2P) + gu * 8;
        pb[q] = Bb + (size_t)wrow * K2P + gu * 8;
        gq[q] = (2 * q + (w >> 1)) & 3;    // wave-uniform gate of this staging group
    }

    // ---- phase 1: K [0,256), gates {0,1,3} ----
    for (int kk = 0; kk < 256; kk += 64) {
        __syncthreads();
        #pragma unroll
        for (int q = 0; q < 4; ++q) {
            GLL(pa[q], As + (q * 32 + w * 8) * 64);
            if (gq[q] != 2) GLL(pb[q], Bs + (q * 32 + w * 8) * 64);
            pa[q] += 64; pb[q] += 64;
        }
        __syncthreads();
        #pragma unroll
        for (int ks = 0; ks < 2; ++ks) {
            const int p = (ks * 4 + l4) ^ l7;
            bf16x8 af[4];
            #pragma unroll
            for (int m = 0; m < 4; ++m)
                af[m] = *(const bf16x8*)(As + (wr * 64 + m * 16 + l15) * 64 + p * 8);
            bf16x8 b0 = *(const bf16x8*)(Bs + (wc * 64 + 0 * 16 + l15) * 64 + p * 8);
            bf16x8 b1 = *(const bf16x8*)(Bs + (wc * 64 + 1 * 16 + l15) * 64 + p * 8);
            bf16x8 b3 = *(const bf16x8*)(Bs + (wc * 64 + 3 * 16 + l15) * 64 + p * 8);
            #pragma unroll
            for (int m = 0; m < 4; ++m) {
                acc[m][0] = __builtin_amdgcn_mfma_f32_16x16x32_bf16(af[m], b0, acc[m][0], 0, 0, 0);
                acc[m][1] = __builtin_amdgcn_mfma_f32_16x16x32_bf16(af[m], b1, acc[m][1], 0, 0, 0);
                acc[m][3] = __builtin_amdgcn_mfma_f32_16x16x32_bf16(af[m], b3, acc[m][3], 0, 0, 0);
            }
        }
    }

    // ---- phase 2: K [256,704), gates {0,1,2} ----
    for (int kk = 256; kk < K2P; kk += 64) {
        __syncthreads();
        #pragma unroll
        for (int q = 0; q < 4; ++q) {
            GLL(pa[q], As + (q * 32 + w * 8) * 64);
            if (gq[q] != 3) GLL(pb[q], Bs + (q * 32 + w * 8) * 64);
            pa[q] += 64; pb[q] += 64;
        }
        __syncthreads();
        #pragma unroll
        for (int ks = 0; ks < 2; ++ks) {
            const int p = (ks * 4 + l4) ^ l7;
            bf16x8 af[4];
            #pragma unroll
            for (int m = 0; m < 4; ++m)
                af[m] = *(const bf16x8*)(As + (wr * 64 + m * 16 + l15) * 64 + p * 8);
            bf16x8 b0 = *(const bf16x8*)(Bs + (wc * 64 + 0 * 16 + l15) * 64 + p * 8);
            bf16x8 b1 = *(const bf16x8*)(Bs + (wc * 64 + 1 * 16 + l15) * 64 + p * 8);
            bf16x8 b2 = *(const bf16x8*)(Bs + (wc * 64 + 2 * 16 + l15) * 64 + p * 8);
            #pragma unroll
            for (int m = 0; m < 4; ++m) {
                acc[m][0] = __builtin_amdgcn_mfma_f32_16x16x32_bf16(af[m], b0, acc[m][0], 0, 0, 0);
                acc[m][1] = __builtin_amdgcn_mfma_f32_16x16x32_bf16(af[m], b1, acc[m][1], 0, 0, 0);
                acc[m][2] = __builtin_amdgcn_mfma_f32_16x16x32_bf16(af[m], b2, acc[m][2], 0, 0, 0);
            }
        }
    }

    // fused GRU epilogue: acc[m][gate][j]; col = c0*32 + wc*16 + l15
    const int col = c0 * 32 + wc * 16 + l15;
    #pragma unroll
    for (int m = 0; m < 4; ++m)
        #pragma unroll
        for (int j = 0; j < 4; ++j) {
            int row = m0 + wr * 64 + m * 16 + l4 * 4 + j;     // batch index
            size_t ridx = (size_t)row * NRIM + n;
            float reset = fsig(acc[m][0][j]);
            float inp   = fsig(acc[m][1][j]);
            float newg  = ftanh_(acc[m][2][j] + reset * acc[m][3][j]);
            float h     = __bfloat162float(A2[ridx * K2P + col]);
            hyB[ridx * HID + col] = __float2bfloat16(newg + inp * (h - newg));
        }
}

// ---------------- K3 GEMM: qkv[(b*16+n)][1280] = hy @ Wqkv^T (coalesced) -----------
__global__ __launch_bounds__(256)
void k3g(const hbf* __restrict__ hyB, const hbf* __restrict__ Wqkv, hbf* __restrict__ qkv)
{
    __shared__ __align__(16) short As[128 * 64];
    __shared__ __align__(16) short Bs[128 * 64];
    const int id = blockIdx.x;
    const int xcd = id & 7, idx = id >> 3;          // idx in [0,320)
    const int n  = xcd + (idx / 160) * 8;
    const int rem = idx % 160;
    const int m0 = (rem / 10) * 128;                // batch-tile base
    const int c0 = (rem % 10) * 128;

    const hbf* A = hyB + (size_t)n * HID + (size_t)m0 * (NRIM * HID);
    const hbf* B = Wqkv + (size_t)n * (1280 * 256) + (size_t)c0 * 256;

    f32x4 acc[4][4];
    f32x4 zz = {0.0f, 0.0f, 0.0f, 0.0f};
    #pragma unroll
    for (int m = 0; m < 4; ++m)
        #pragma unroll
        for (int nb = 0; nb < 4; ++nb) acc[m][nb] = zz;

    gemm_core64(A, NRIM * HID, B, 256, 256, As, Bs, acc);

    const int t = threadIdx.x;
    const int w = t >> 6, lane = t & 63, l15 = lane & 15, l4 = lane >> 4;
    const int wr = w >> 1, wc = w & 1;
    #pragma unroll
    for (int m = 0; m < 4; ++m)
        #pragma unroll
        for (int nb = 0; nb < 4; ++nb) {
            int col = c0 + wc * 64 + nb * 16 + l15;
            int rb  = m0 + wr * 64 + m * 16 + l4 * 4;   // batch base for this lane
            #pragma unroll
            for (int j = 0; j < 4; ++j)
                qkv[((size_t)(rb + j) * 16 + n) * 1280 + col] = __float2bfloat16(acc[m][nb][j]);
        }
}

// ---------------- K4: attention, MFMA + LDS V-transpose, block per b ---------------
__global__ __launch_bounds__(256)
void k4_attn(const hbf* __restrict__ qkv, const float* __restrict__ maskg,
             hbf* __restrict__ ctx)
{
    const int b = blockIdx.x;
    const int t = threadIdx.x;
    const int w = t >> 6, lane = t & 63;
    const int l15 = lane & 15, g = lane >> 4;

    __shared__ hbf vS[16 * 1024];   // V[m][h*256+d], 32KB

    // stage V coalesced: thread (r=t>>4, c=t&15) copies 8x16B of row r
    {
        const int r = t >> 4, c = t & 15;
        const uint4* src = (const uint4*)(qkv + (size_t)(b * 16 + r) * 1280 + 256);
        uint4* dst = (uint4*)(vS + r * 1024);
        #pragma unroll
        for (int i = 0; i < 8; ++i) dst[c + i * 16] = src[c + i * 16];
    }

    // S^T = K @ Q^T : lane holds S[m=4g+j][n=l15]
    const hbf* qrow = qkv + (size_t)(b * 16 + l15) * 1280 + w * 32 + g * 8;
    bf16x8 qf = *(const bf16x8*)(qrow);
    bf16x8 kf = *(const bf16x8*)(qrow + 128);
    f32x4 s = {0.f, 0.f, 0.f, 0.f};
    s = __builtin_amdgcn_mfma_f32_16x16x32_bf16(kf, qf, s, 0, 0, 0);

    const float scale = 0.17677669529663687f;
    float v0 = s[0] * scale, v1 = s[1] * scale, v2 = s[2] * scale, v3 = s[3] * scale;
    float mx = fmaxf(fmaxf(v0, v1), fmaxf(v2, v3));
    mx = fmaxf(mx, __shfl_xor(mx, 16));
    mx = fmaxf(mx, __shfl_xor(mx, 32));
    float e0 = __expf(v0 - mx), e1 = __expf(v1 - mx);
    float e2 = __expf(v2 - mx), e3 = __expf(v3 - mx);
    float sm = e0 + e1 + e2 + e3;
    sm += __shfl_xor(sm, 16);
    sm += __shfl_xor(sm, 32);
    float inv = maskg[b * NRIM + l15] / sm;   // row-mask * softmax-normalize

    // P^T regs -> B-fragment for PV mfma (lane n=l15 needs m=8g..8g+7; zero g>=2)
    unsigned u0 = packbf(e0 * inv, e1 * inv);
    unsigned u1 = packbf(e2 * inv, e3 * inv);
    int sl = l15 + (g << 5);
    unsigned f0 = __shfl((int)u0, sl);
    unsigned f1 = __shfl((int)u1, sl);
    unsigned f2 = __shfl((int)u0, sl + 16);
    unsigned f3 = __shfl((int)u1, sl + 16);
    if (lane >= 32) { f0 = 0; f1 = 0; f2 = 0; f3 = 0; }
    union { unsigned u[4]; bf16x8 v; } pf;
    pf.u[0] = f0; pf.u[1] = f1; pf.u[2] = f2; pf.u[3] = f3;

    __syncthreads();

    // PV: A-frag lane (row=l15 -> d_local, g -> m-group) from LDS column reads
    const unsigned short* vsu = (const unsigned short*)vS;
    const int vbase = (8 * (g & 1)) * 1024 + w * 256 + l15;   // + e*1024 + dc*16
    hbf* crow = ctx + (size_t)(b * 16 + l15) * 1024 + w * 256 + g * 4;
    #pragma unroll
    for (int dc = 0; dc < 16; ++dc) {
        union { unsigned short u[8]; bf16x8 v; } vf;
        #pragma unroll
        for (int e = 0; e < 8; ++e)
            vf.u[e] = vsu[vbase + e * 1024 + dc * 16];
        f32x4 o = {0.f, 0.f, 0.f, 0.f};
        o = __builtin_amdgcn_mfma_f32_16x16x32_bf16(vf.v, pf.v, o, 0, 0, 0);
        unsigned lo = packbf(o[0], o[1]);
        unsigned hi = packbf(o[2], o[3]);
        *(uint2*)(crow + dc * 16) = make_uint2(lo, hi);
    }
}

// ---------------- K5 GEMM: out = mask ? ctx @ Wout^T + hy : hs ---------------------
__global__ __launch_bounds__(256)
void k5g(const hbf* __restrict__ ctx, const hbf* __restrict__ Wout,
         const hbf* __restrict__ hyB, const float* __restrict__ hs,
         const float* __restrict__ maskg, float* __restrict__ out)
{
    __shared__ __align__(16) short As[128 * 64];
    __shared__ __align__(16) short Bs[128 * 64];
    const int id = blockIdx.x;
    const int xcd = id & 7, idx = id >> 3;          // idx in [0,64)
    const int n  = xcd + ((idx >> 5) << 3);
    const int rem = idx & 31;
    const int m0 = (rem >> 1) * 128;
    const int c0 = (rem & 1) * 128;

    const hbf* A = ctx + (size_t)n * 1024 + (size_t)m0 * (NRIM * 1024);
    const hbf* B = Wout + (size_t)n * (256 * 1024) + (size_t)c0 * 1024;

    f32x4 acc[4][4];
    f32x4 zz = {0.0f, 0.0f, 0.0f, 0.0f};
    #pragma unroll
    for (int m = 0; m < 4; ++m)
        #pragma unroll
        for (int nb = 0; nb < 4; ++nb) acc[m][nb] = zz;

    gemm_core64(A, NRIM * 1024, B, 1024, 1024, As, Bs, acc);

    const int t = threadIdx.x;
    const int w = t >> 6, lane = t & 63, l15 = lane & 15, l4 = lane >> 4;
    const int wr = w >> 1, wc = w & 1;
    #pragma unroll
    for (int m = 0; m < 4; ++m)
        #pragma unroll
        for (int nb = 0; nb < 4; ++nb) {
            int col = c0 + wc * 64 + nb * 16 + l15;
            #pragma unroll
            for (int j = 0; j < 4; ++j) {
                int row = m0 + wr * 64 + m * 16 + l4 * 4 + j;
                size_t idx2 = ((size_t)row * NRIM + n) * HID + col;
                float mk = maskg[row * NRIM + n];
                out[idx2] = (mk > 0.5f) ? (acc[m][nb][j] + __bfloat162float(hyB[idx2]))
                                        : hs[idx2];
            }
        }
}

extern "C" void kernel_launch(void* const* d_in, const int* in_sizes, int n_in,
                              void* d_out, int out_size, void* d_ws, size_t ws_size,
                              hipStream_t stream) {
    const float* x       = (const float*)d_in[0];
    const float* hs      = (const float*)d_in[1];
    const float* option  = (const float*)d_in[2];
    const float* value_w = (const float*)d_in[3];
    const float* value_b = (const float*)d_in[4];
    const float* p_w     = (const float*)d_in[5];
    const float* p_b     = (const float*)d_in[6];
    const float* x2h_w   = (const float*)d_in[7];
    const float* h2h_w   = (const float*)d_in[8];
    const float* q_w     = (const float*)d_in[9];
    const float* k_w     = (const float*)d_in[10];
    const float* v_w     = (const float*)d_in[11];
    const float* out_w   = (const float*)d_in[12];
    float* out = (float*)d_out;

    char* ws = (char*)d_ws;
    hbf* A2   = (hbf*)(ws);
    hbf* ctx  = (hbf*)(ws);
    size_t off = 67108864;
    hbf* qkv  = (hbf*)(ws + off);
    off += 83886080;
    hbf* W2   = (hbf*)(ws + off); off += 23068672;   // [16][1024][704]
    hbf* Wqkv = (hbf*)(ws + off); off += 10485760;   // [16][1280][256]
    hbf* Wout = (hbf*)(ws + off); off += 8388608;    // [16][256][1024]
    hbf* hyB  = (hbf*)(ws + off); off += 16777216;   // [32768][256]
    float* vl0   = (float*)(ws + off); off += 4194304;   // [2048][512] f32
    hbf* xB   = (hbf*)(ws + off); off += 2097152;    // [2048][512] bf16
    hbf* Wv   = (hbf*)(ws + off); off += 524288;     // [512][512] bf16
    float* p0g   = (float*)(ws + off); off += 131072;
    float* maskg = (float*)(ws + off); off += 131072;

    mega_prep<<<dim3(20364), dim3(256), 0, stream>>>(
        h2h_w, x2h_w, q_w, k_w, v_w, out_w, value_w, option, p_w, p_b, x,
        W2, Wqkv, Wout, Wv, p0g, maskg, xB);

    k1v<<<dim3(64), dim3(256), 0, stream>>>(xB, Wv, value_b, vl0);
    k1b_a2<<<dim3(BATCH), dim3(256), 0, stream>>>(hs, vl0, p0g, maskg, value_b, A2);

    k2g<<<dim3(2048), dim3(256), 0, stream>>>(A2, W2, hyB);

    k3g<<<dim3(2560), dim3(256), 0, stream>>>(hyB, Wqkv, qkv);

    k4_attn<<<dim3(BATCH), dim3(256), 0, stream>>>(qkv, maskg, ctx);

    k5g<<<dim3(512), dim3(256), 0, stream>>>(ctx, Wout, hyB, hs, maskg, out);
}